// Round 14
// baseline (390.951 us; speedup 1.0000x reference)
//
#include <hip/hip_runtime.h>
#include <math.h>

typedef unsigned short u16t;
typedef unsigned int   u32t;
typedef __bf16 bf16x2 __attribute__((ext_vector_type(2)));
typedef __bf16 bf16x8 __attribute__((ext_vector_type(8)));
typedef float  f32x4  __attribute__((ext_vector_type(4)));

#define DEV static __device__ __forceinline__

DEV u16t bfc(float x){ __bf16 b = (__bf16)x; return __builtin_bit_cast(u16t, b); }
DEV u32t pkbf(float a, float b){ bf16x2 v = {(__bf16)a, (__bf16)b}; return __builtin_bit_cast(u32t, v); }
DEV float flc(u16t u){ return __uint_as_float(((u32t)u)<<16); }
DEV u32t pk2(u16t a, u16t b){ return (u32t)a | ((u32t)b<<16); }
DEV f32x4 fz4(){ f32x4 z = {0.f,0.f,0.f,0.f}; return z; }
DEV bf16x8 bz8(){ uint4 z = make_uint4(0u,0u,0u,0u); return __builtin_bit_cast(bf16x8, z); }
DEV f32x4 MFMA(bf16x8 a, bf16x8 b, f32x4 c){ return __builtin_amdgcn_mfma_f32_16x16x32_bf16(a,b,c,0,0,0); }

// ---------------- prep: LN(h) (blocks 0..511) + tiled coalesced weight transposes (512..1023) ----------------
__global__ __launch_bounds__(256) void kprep(
    const float* __restrict__ h, const float* __restrict__ g, const float* __restrict__ bb, u16t* __restrict__ hln,
    const float* __restrict__ A, u16t* __restrict__ oA,
    const float* __restrict__ B, u16t* __restrict__ oB,
    const float* __restrict__ C, u16t* __restrict__ oC,
    const float* __restrict__ D, u16t* __restrict__ oD)
{
  if (blockIdx.x < 512){
    int wv = threadIdx.x >> 6, lane = threadIdx.x & 63;
    int row = blockIdx.x*4 + wv;
    const float4* rp = reinterpret_cast<const float4*>(h + (size_t)row*512);
    float4 v0 = rp[lane], v1 = rp[lane+64];
    float s = v0.x+v0.y+v0.z+v0.w + v1.x+v1.y+v1.z+v1.w;
    float q = v0.x*v0.x+v0.y*v0.y+v0.z*v0.z+v0.w*v0.w + v1.x*v1.x+v1.y*v1.y+v1.z*v1.z+v1.w*v1.w;
    #pragma unroll
    for (int m=1;m<64;m<<=1){ s += __shfl_xor(s,m); q += __shfl_xor(q,m); }
    float mean = s*(1.f/512.f), var = q*(1.f/512.f)-mean*mean, rs = rsqrtf(var+1e-5f);
    const float4* gp = reinterpret_cast<const float4*>(g);
    const float4* bp = reinterpret_cast<const float4*>(bb);
    float4 g0=gp[lane], g1=gp[lane+64], b0=bp[lane], b1=bp[lane+64];
    u16t* op = hln + (size_t)row*512;
    uint2 o0, o1;
    o0.x = pkbf((v0.x-mean)*rs*g0.x+b0.x, (v0.y-mean)*rs*g0.y+b0.y);
    o0.y = pkbf((v0.z-mean)*rs*g0.z+b0.z, (v0.w-mean)*rs*g0.w+b0.w);
    o1.x = pkbf((v1.x-mean)*rs*g1.x+b1.x, (v1.y-mean)*rs*g1.y+b1.y);
    o1.y = pkbf((v1.z-mean)*rs*g1.z+b1.z, (v1.w-mean)*rs*g1.w+b1.w);
    reinterpret_cast<uint2*>(op)[lane]    = o0;
    reinterpret_cast<uint2*>(op)[lane+64] = o1;
    return;
  }
  __shared__ u16t Ts[64][68];
  int bid = blockIdx.x - 512;
  const float* src; u16t* dst; int K, N, perm = 0;
  if      (bid < 192){             src=A;  dst=oA;  K=512;  N=1536; }
  else if (bid < 256){ bid-=192;   src=B;  dst=oB;  K=512;  N=512;  perm=1; }
  else if (bid < 384){ bid-=256;   src=C;  dst=oC;  K=512;  N=1024; }
  else {               bid-=384;   src=D;  dst=oD;  K=1024; N=512;  }
  const int ntn = N>>6;
  const int kt = bid / ntn, nt = bid % ntn;
  const int k0 = kt*64, n0 = nt*64;
  const int t = threadIdx.x, c = t&63, rr = t>>6;
  #pragma unroll
  for (int i=0;i<16;i++){
    int j = rr + i*4;
    int ks = perm ? (j*8 + kt) : (k0 + j);
    Ts[j][c] = bfc(src[(size_t)ks*N + n0 + c]);
  }
  __syncthreads();
  #pragma unroll
  for (int i=0;i<16;i++){
    int n = rr + i*4;
    dst[(size_t)(n0+n)*K + k0 + c] = Ts[c][n];
  }
}

// ---------------- QKV GEMM ----------------
__global__ __launch_bounds__(256) void kqkv(const u16t* __restrict__ hln, const u16t* __restrict__ Wt,
    const float* __restrict__ bias, u16t* __restrict__ Qb, u16t* __restrict__ Kb, u16t* __restrict__ Vt)
{
  __shared__ __align__(16) u16t As[16][520];
  __shared__ __align__(16) u16t Cs[16][1024];
  const int r0 = blockIdx.x*16, t = threadIdx.x;
  const int b8 = (r0 >> 9) * 8, pos0 = r0 & 511;
  {
    int row = t>>4, seg = t&15;
    const uint4* src = reinterpret_cast<const uint4*>(hln + (size_t)(r0+row)*512 + seg*32);
    uint4* dst = reinterpret_cast<uint4*>(&As[row][seg*32]);
    dst[0]=src[0]; dst[1]=src[1]; dst[2]=src[2]; dst[3]=src[3];
  }
  __syncthreads();
  const int wv = t>>6, lane = t&63;
  const int frow = lane&15, kgrp = (lane>>4)*8, rbase = (lane>>4)*4;
  for (int nt=0; nt<24; nt++){
    int n0 = (wv*24+nt)*16;
    f32x4 acc = fz4();
    for (int k0=0;k0<512;k0+=32){
      bf16x8 af = *reinterpret_cast<const bf16x8*>(&As[frow][k0+kgrp]);
      bf16x8 bf_ = *reinterpret_cast<const bf16x8*>(Wt + (size_t)(n0+frow)*512 + k0+kgrp);
      acc = MFMA(af,bf_,acc);
    }
    int col = n0 + frow;
    float bs = bias[col];
    if (n0 < 1024){
      #pragma unroll
      for (int r=0;r<4;r++) Cs[rbase+r][col] = bfc(acc[r]+bs);
    } else {
      int cc = col - 1024, dv = cc>>3, hq = cc&7;
      ushort4 u4 = make_ushort4(bfc(acc[0]+bs), bfc(acc[1]+bs), bfc(acc[2]+bs), bfc(acc[3]+bs));
      *reinterpret_cast<ushort4*>(Vt + ((size_t)(b8+hq)*64 + dv)*512 + pos0 + rbase) = u4;
    }
  }
  __syncthreads();
  {
    int pair = t>>1, halfq = t&1;
    int hq = pair>>4, lq = pair&15, d0 = halfq*32;
    int pos = pos0 + lq;
    u16t* qdst = Qb + ((size_t)(b8+hq)*512 + pos)*64 + d0;
    u16t* kdst = Kb + ((size_t)(b8+hq)*512 + pos)*64 + d0;
    #pragma unroll
    for (int v2=0; v2<4; v2++){
      uint4 u, uk;
      u.x  = pk2(Cs[lq][(d0+v2*8+0)*8+hq], Cs[lq][(d0+v2*8+1)*8+hq]);
      u.y  = pk2(Cs[lq][(d0+v2*8+2)*8+hq], Cs[lq][(d0+v2*8+3)*8+hq]);
      u.z  = pk2(Cs[lq][(d0+v2*8+4)*8+hq], Cs[lq][(d0+v2*8+5)*8+hq]);
      u.w  = pk2(Cs[lq][(d0+v2*8+6)*8+hq], Cs[lq][(d0+v2*8+7)*8+hq]);
      uk.x = pk2(Cs[lq][512+(d0+v2*8+0)*8+hq], Cs[lq][512+(d0+v2*8+1)*8+hq]);
      uk.y = pk2(Cs[lq][512+(d0+v2*8+2)*8+hq], Cs[lq][512+(d0+v2*8+3)*8+hq]);
      uk.z = pk2(Cs[lq][512+(d0+v2*8+4)*8+hq], Cs[lq][512+(d0+v2*8+5)*8+hq]);
      uk.w = pk2(Cs[lq][512+(d0+v2*8+6)*8+hq], Cs[lq][512+(d0+v2*8+7)*8+hq]);
      reinterpret_cast<uint4*>(qdst)[v2] = u;
      reinterpret_cast<uint4*>(kdst)[v2] = uk;
    }
  }
}

// ---------------- fused e-stream (proven 259us config) + folded PV; explicit 128-VGPR budget ----------------
// grid (32 lblk, 4 chunk, 4 b) = 512 blocks = 2/CU. wave wv: head wv (QK+PV, 16 l-rows) + l-rows {2wv,2wv+1}.
__global__ __launch_bounds__(512,4) __attribute__((amdgpu_num_vgpr(128))) void kattnF(
    const float* __restrict__ e, const float* __restrict__ lng, const float* __restrict__ lnb,
    const float* __restrict__ WE, const float* __restrict__ bE,
    const float* __restrict__ WG, const float* __restrict__ bG,
    const u16t* __restrict__ Qb, const u16t* __restrict__ Kb, const u16t* __restrict__ Vt,
    const float* __restrict__ WOe, const float* __restrict__ bOe,
    const float* __restrict__ flg, const float* __restrict__ flb,
    const float* __restrict__ We1, const float* __restrict__ be1,
    const float* __restrict__ We2, const float* __restrict__ be2,
    u16t* __restrict__ Vp, float* __restrict__ Sp, float* __restrict__ Dp,
    float* __restrict__ eout)
{
  __shared__ __align__(16) u16t Eln[256][72];   // LN(e); reused e_f/X1; f32 Vo at epilogue
  __shared__ u16t EGb[256][18];
  __shared__ __align__(16) u16t Hl[256][8];
  __shared__ __align__(16) u16t Pgs[16][8][16];
  __shared__ __align__(16) u16t WEGt[16][72];
  __shared__ __align__(16) u16t We1t[64][72];
  __shared__ __align__(16) u16t We2t[64][72];
  __shared__ __align__(16) u16t WOeT[64][8];
  __shared__ float lgs[64], lbs[64], flgs[64], flbs[64], bOes[64], be1s[64], be2s[64];
  __shared__ float bEs[8], bGs[8];

  const int t = threadIdx.x;
  const int b = blockIdx.z, lblk = blockIdx.x, chunk = blockIdx.y;
  const int l0 = lblk*16, m0g = chunk*128, b8 = b*8;

  if (t < 64){
    lgs[t]=lng[t]; lbs[t]=lnb[t]; flgs[t]=flg[t]; flbs[t]=flb[t];
    bOes[t]=bOe[t]; be1s[t]=be1[t]; be2s[t]=be2[t];
  }
  if (t < 8){ bEs[t]=bE[t]; bGs[t]=bG[t]; }
  for (int i=t; i<1024; i+=512){
    int n = i>>6, k = i&63;
    WEGt[n][k] = bfc(n<8 ? WE[k*8+n] : WG[k*8+(n-8)]);
  }
  for (int i=t; i<4096; i+=512){
    int n=i>>6, k=i&63;
    We1t[n][k] = bfc(We1[k*64+n]);
    We2t[n][k] = bfc(We2[k*64+n]);
  }
  {
    int n=t>>3, hh=t&7;
    WOeT[n][hh] = bfc(WOe[hh*64+n]);
  }
  __syncthreads();

  const int wv = t>>6, lane = t&63;
  const int frow = lane&15, kgrp = (lane>>4)*8, rbase = (lane>>4)*4;

  bf16x8 qf[2];
  #pragma unroll
  for (int kk=0;kk<2;kk++)
    qf[kk] = *reinterpret_cast<const bf16x8*>(Qb + ((size_t)(b8+wv)*512 + l0+frow)*64 + kk*32 + kgrp);

  float Ssum[4] = {0.f,0.f,0.f,0.f}, Dsum[4] = {0.f,0.f,0.f,0.f};
  f32x4 accV[4];
  #pragma unroll
  for (int d=0;d<4;d++) accV[d]=fz4();

  const float* ebs[2];
  #pragma unroll
  for (int ti=0; ti<2; ti++)
    ebs[ti] = e + ((size_t)((b*512 + l0 + 2*wv+ti)*512) + m0g + frow)*64 + rbase;

  float4 xr[2][4];
  #pragma unroll
  for (int ti=0; ti<2; ti++)
    #pragma unroll
    for (int nb=0; nb<4; nb++)
      xr[ti][nb] = *reinterpret_cast<const float4*>(ebs[ti] + nb*16);

  #pragma unroll 1
  for (int mt=0; mt<8; mt++){
    const int m0 = m0g + mt*16;
    // ---- P1: LN(e)
    #pragma unroll
    for (int ti=0; ti<2; ti++){
      const int T = 2*wv + ti;
      float s_=0.f, q_=0.f;
      #pragma unroll
      for (int nb=0; nb<4; nb++){
        float4 v = xr[ti][nb];
        s_ += v.x+v.y+v.z+v.w;
        q_ += v.x*v.x+v.y*v.y+v.z*v.z+v.w*v.w;
      }
      s_ += __shfl_xor(s_,16); q_ += __shfl_xor(q_,16);
      s_ += __shfl_xor(s_,32); q_ += __shfl_xor(q_,32);
      float mean = s_*(1.f/64.f), var = q_*(1.f/64.f)-mean*mean, rs = rsqrtf(var+1e-5f);
      #pragma unroll
      for (int nb=0; nb<4; nb++){
        int n = nb*16 + rbase;
        float4 v = xr[ti][nb];
        uint2 uv;
        uv.x = pkbf((v.x-mean)*rs*lgs[n  ]+lbs[n  ], (v.y-mean)*rs*lgs[n+1]+lbs[n+1]);
        uv.y = pkbf((v.z-mean)*rs*lgs[n+2]+lbs[n+2], (v.w-mean)*rs*lgs[n+3]+lbs[n+3]);
        *reinterpret_cast<uint2*>(&Eln[T*16+frow][n]) = uv;
      }
    }
    // ---- P2: E||G
    #pragma unroll
    for (int ti=0; ti<2; ti++){
      int T = wv*2+ti;
      bf16x8 a0 = *reinterpret_cast<const bf16x8*>(&Eln[T*16+frow][kgrp]);
      bf16x8 a1 = *reinterpret_cast<const bf16x8*>(&Eln[T*16+frow][32+kgrp]);
      bf16x8 w0 = *reinterpret_cast<const bf16x8*>(&WEGt[frow][kgrp]);
      bf16x8 w1 = *reinterpret_cast<const bf16x8*>(&WEGt[frow][32+kgrp]);
      f32x4 acc = fz4(); acc = MFMA(a0,w0,acc); acc = MFMA(a1,w1,acc);
      #pragma unroll
      for (int r=0;r<4;r++) EGb[T*16+rbase+r][frow] = bfc(acc[r]);
    }
    __syncthreads();
    // ---- P3: QK^T + combine
    {
      const u16t* kb = Kb + ((size_t)(b8+wv)*512 + m0)*64 + frow*64 + kgrp;
      bf16x8 kf0 = *reinterpret_cast<const bf16x8*>(kb);
      bf16x8 kf1 = *reinterpret_cast<const bf16x8*>(kb + 32);
      f32x4 aq = fz4();
      aq = MFMA(qf[0], kf0, aq);
      aq = MFMA(qf[1], kf1, aq);
      #pragma unroll
      for (int r=0;r<4;r++){
        int lrow = rbase + r;
        int eidx = lrow*16 + frow;
        float ah = aq[r]*0.125f;
        ah = fminf(fmaxf(ah, -5.f), 5.f);
        float Ev = flc(EGb[eidx][wv])   + bEs[wv];
        float Gv = flc(EGb[eidx][8+wv]) + bGs[wv];
        float Hv = ah + Ev;
        float P = __expf(Hv);
        float g = 1.f/(1.f+__expf(-Gv));
        Ssum[r] += P; Dsum[r] += g;
        Hl[eidx][wv] = bfc(Hv);
        Pgs[lrow][wv][frow] = bfc(P*g);
      }
    }
    // ---- PV
    {
      bf16x8 pa = (kgrp<16)
        ? *reinterpret_cast<const bf16x8*>(&Pgs[frow][wv][kgrp]) : bz8();
      #pragma unroll
      for (int db=0; db<4; db++){
        bf16x8 vb = (kgrp<16)
          ? *reinterpret_cast<const bf16x8*>(Vt + ((size_t)(b8+wv)*64 + db*16+frow)*512 + m0 + kgrp)
          : bz8();
        accV[db] = MFMA(pa, vb, accV[db]);
      }
    }
    __syncthreads();
    // ---- P5: edge FFN
    #pragma unroll
    for (int ti=0; ti<2; ti++){
      const int T = 2*wv + ti;
      bf16x8 hf_ = bz8();
      if (kgrp==0) hf_ = *reinterpret_cast<const bf16x8*>(&Hl[T*16+frow][0]);
      f32x4 e1a[4];
      #pragma unroll
      for (int nb=0; nb<4; nb++){
        bf16x8 wf = bz8();
        if (kgrp==0) wf = *reinterpret_cast<const bf16x8*>(&WOeT[nb*16][0] + frow*8);
        e1a[nb] = MFMA(wf, hf_, fz4());
      }
      #pragma unroll
      for (int nb=0; nb<4; nb++){
        int n = nb*16 + rbase;
        e1a[nb][0] += bOes[n  ] + xr[ti][nb].x;
        e1a[nb][1] += bOes[n+1] + xr[ti][nb].y;
        e1a[nb][2] += bOes[n+2] + xr[ti][nb].z;
        e1a[nb][3] += bOes[n+3] + xr[ti][nb].w;
      }
      if (mt+1 < 8){
        #pragma unroll
        for (int nb=0; nb<4; nb++)
          xr[ti][nb] = *reinterpret_cast<const float4*>(ebs[ti] + (size_t)(mt+1)*1024 + nb*16);
      }
      {
        float s_=0.f, q_=0.f;
        #pragma unroll
        for (int nb=0; nb<4; nb++){
          #pragma unroll
          for (int r=0;r<4;r++){ float v = e1a[nb][r]; s_ += v; q_ += v*v; }
        }
        s_ += __shfl_xor(s_,16); q_ += __shfl_xor(q_,16);
        s_ += __shfl_xor(s_,32); q_ += __shfl_xor(q_,32);
        float mean = s_*(1.f/64.f), var = q_*(1.f/64.f)-mean*mean, rs = rsqrtf(var+1e-5f);
        #pragma unroll
        for (int nb=0; nb<4; nb++){
          int n = nb*16 + rbase;
          uint2 uv;
          uv.x = pkbf((e1a[nb][0]-mean)*rs*flgs[n  ]+flbs[n  ], (e1a[nb][1]-mean)*rs*flgs[n+1]+flbs[n+1]);
          uv.y = pkbf((e1a[nb][2]-mean)*rs*flgs[n+2]+flbs[n+2], (e1a[nb][3]-mean)*rs*flgs[n+3]+flbs[n+3]);
          *reinterpret_cast<uint2*>(&Eln[T*16+frow][n]) = uv;
        }
      }
      {
        bf16x8 x0 = *reinterpret_cast<const bf16x8*>(&Eln[T*16+frow][kgrp]);
        bf16x8 x1 = *reinterpret_cast<const bf16x8*>(&Eln[T*16+frow][32+kgrp]);
        f32x4 acc1[4];
        #pragma unroll
        for (int nb=0;nb<4;nb++){
          bf16x8 w0 = *reinterpret_cast<const bf16x8*>(&We1t[nb*16+frow][kgrp]);
          bf16x8 w1 = *reinterpret_cast<const bf16x8*>(&We1t[nb*16+frow][32+kgrp]);
          f32x4 a_ = fz4(); a_ = MFMA(w0,x0,a_); a_ = MFMA(w1,x1,a_);
          acc1[nb] = a_;
        }
        #pragma unroll
        for (int nb=0;nb<4;nb++){
          int n = nb*16 + rbase;
          float v0 = acc1[nb][0] + be1s[n  ]; v0 = v0>0.f ? v0 : (__expf(v0)-1.f);
          float v1 = acc1[nb][1] + be1s[n+1]; v1 = v1>0.f ? v1 : (__expf(v1)-1.f);
          float v2 = acc1[nb][2] + be1s[n+2]; v2 = v2>0.f ? v2 : (__expf(v2)-1.f);
          float v3 = acc1[nb][3] + be1s[n+3]; v3 = v3>0.f ? v3 : (__expf(v3)-1.f);
          uint2 uv;
          uv.x = pkbf(v0, v1);
          uv.y = pkbf(v2, v3);
          *reinterpret_cast<uint2*>(&Eln[T*16+frow][n]) = uv;
        }
      }
      {
        bf16x8 x0 = *reinterpret_cast<const bf16x8*>(&Eln[T*16+frow][kgrp]);
        bf16x8 x1 = *reinterpret_cast<const bf16x8*>(&Eln[T*16+frow][32+kgrp]);
        float* eob = eout + ((size_t)((b*512 + l0 + T)*512) + m0 + frow)*64 + rbase;
        #pragma unroll
        for (int nb=0;nb<4;nb++){
          bf16x8 w0 = *reinterpret_cast<const bf16x8*>(&We2t[nb*16+frow][kgrp]);
          bf16x8 w1 = *reinterpret_cast<const bf16x8*>(&We2t[nb*16+frow][32+kgrp]);
          f32x4 a_ = fz4(); a_ = MFMA(w0,x0,a_); a_ = MFMA(w1,x1,a_);
          int n = nb*16 + rbase;
          float4 o;
          o.x = a_[0] + be2s[n  ] + e1a[nb][0];
          o.y = a_[1] + be2s[n+1] + e1a[nb][1];
          o.z = a_[2] + be2s[n+2] + e1a[nb][2];
          o.w = a_[3] + be2s[n+3] + e1a[nb][3];
          *reinterpret_cast<float4*>(eob + nb*16) = o;
        }
      }
    }
  }

  #pragma unroll
  for (int r=0;r<4;r++){
    float sv = Ssum[r], dv = Dsum[r];
    #pragma unroll
    for (int msk=1; msk<16; msk<<=1){ sv += __shfl_xor(sv, msk); dv += __shfl_xor(dv, msk); }
    int lrow = rbase + r;
    if (frow == 0){
      size_t idx = ((size_t)(b*512 + l0 + lrow)*8 + wv)*4 + chunk;
      Sp[idx] = sv; Dp[idx] = dv;
    }
  }
  __syncthreads();
  float* Vo = reinterpret_cast<float*>(&Eln[0][0]);   // [16][512] f32
  #pragma unroll
  for (int db=0; db<4; db++){
    #pragma unroll
    for (int r=0;r<4;r++)
      Vo[(size_t)(rbase+r)*512 + wv*64 + db*16 + frow] = accV[db][r];
  }
  __syncthreads();
  {
    int row = t>>5, i = t&31;
    u16t* vpb = Vp + ((size_t)(chunk*2048 + b*512 + l0 + row))*512 + i*16;
    const float* vsrc = &Vo[(size_t)row*512 + i*16];
    uint4 o0, o1;
    o0.x = pkbf(vsrc[0],  vsrc[1]);  o0.y = pkbf(vsrc[2],  vsrc[3]);
    o0.z = pkbf(vsrc[4],  vsrc[5]);  o0.w = pkbf(vsrc[6],  vsrc[7]);
    o1.x = pkbf(vsrc[8],  vsrc[9]);  o1.y = pkbf(vsrc[10], vsrc[11]);
    o1.z = pkbf(vsrc[12], vsrc[13]); o1.w = pkbf(vsrc[14], vsrc[15]);
    reinterpret_cast<uint4*>(vpb)[0] = o0;
    reinterpret_cast<uint4*>(vpb)[1] = o1;
  }
}

// ---------------- finalize: Va = (sum_chunks Vp) * log1p(deg)/S ----------------
__global__ __launch_bounds__(256) void kvfin(const u16t* __restrict__ Vp,
    const float* __restrict__ Sp, const float* __restrict__ Dp, u16t* __restrict__ Va)
{
  const int row = blockIdx.x;
  const int t = threadIdx.x;
  __shared__ float scl[8];
  if (t < 8){
    const float* sp = Sp + ((size_t)row*8 + t)*4;
    const float* dp = Dp + ((size_t)row*8 + t)*4;
    float S = sp[0]+sp[1]+sp[2]+sp[3];
    float D = dp[0]+dp[1]+dp[2]+dp[3];
    scl[t] = log1pf(D)/S;
  }
  __syncthreads();
  int c = t*2;
  float v0=0.f, v1=0.f;
  #pragma unroll
  for (int ch=0; ch<4; ch++){
    u32t u = *reinterpret_cast<const u32t*>(Vp + ((size_t)(ch*2048 + row))*512 + c);
    v0 += flc((u16t)(u & 0xffffu));
    v1 += flc((u16t)(u >> 16));
  }
  float s = scl[c>>6];
  *reinterpret_cast<u32t*>(Va + (size_t)row*512 + c) = pkbf(v0*s, v1*s);
}

// ---------------- N-split GEMM ----------------
__global__ __launch_bounds__(256) void kgemmNS(const u16t* __restrict__ A, const u16t* __restrict__ Bt,
    const float* __restrict__ bias, const float* __restrict__ res,
    float* __restrict__ outf, u16t* __restrict__ outb, int N, int K, int do_elu)
{
  __shared__ __align__(16) u16t As[16][1032];
  const int r0 = blockIdx.x*16, t = threadIdx.x;
  {
    int row = t>>4, seg = t&15, cnt = K>>4;
    const uint4* src = reinterpret_cast<const uint4*>(A + (size_t)(r0+row)*K + seg*cnt);
    uint4* dst = reinterpret_cast<uint4*>(&As[row][seg*cnt]);
    for (int i=0;i<(cnt>>3);i++) dst[i] = src[i];
  }
  __syncthreads();
  const int wv = t>>6, lane = t&63;
  const int frow = lane&15, kgrp = (lane>>4)*8, rbase = (lane>>4)*4;
  int n0 = (blockIdx.y*4 + wv)*16;
  f32x4 acc = fz4();
  for (int k0=0;k0<K;k0+=32){
    bf16x8 af = *reinterpret_cast<const bf16x8*>(&As[frow][k0+kgrp]);
    bf16x8 bf_ = *reinterpret_cast<const bf16x8*>(Bt + (size_t)(n0+frow)*K + k0+kgrp);
    acc = MFMA(af,bf_,acc);
  }
  int col = n0 + frow;
  float bs = bias[col];
  #pragma unroll
  for (int r=0;r<4;r++){
    size_t row = (size_t)(r0 + rbase + r);
    float v = acc[r] + bs;
    if (do_elu) v = v>0.f ? v : (__expf(v)-1.f);
    if (res)  v += res[row*N + col];
    if (outf) outf[row*N + col] = v;
    if (outb) outb[row*N + col] = bfc(v);
  }
}

// ---------------- fused LN + N-split GEMM + elu: U = elu(LN(h1) @ Bt^T + bias) ----------------
// grid (128, 16): block LNs its 16 rows of h1 (redundant per N-block, L2-hot) then GEMMs its 64-col slice.
__global__ __launch_bounds__(256) void kgemmLN(const float* __restrict__ H1in,
    const float* __restrict__ lg, const float* __restrict__ lb,
    const u16t* __restrict__ Bt, const float* __restrict__ bias,
    u16t* __restrict__ outb, int N, int K)
{
  __shared__ __align__(16) u16t As[16][520];
  const int r0 = blockIdx.x*16, t = threadIdx.x;
  {
    int row = t>>4, seg = t&15;
    const float4* rp = reinterpret_cast<const float4*>(H1in + (size_t)(r0+row)*512 + seg*32);
    float4 v[8];
    float s_=0.f, q_=0.f;
    #pragma unroll
    for (int i=0;i<8;i++){
      v[i] = rp[i];
      s_ += v[i].x+v[i].y+v[i].z+v[i].w;
      q_ += v[i].x*v[i].x+v[i].y*v[i].y+v[i].z*v[i].z+v[i].w*v[i].w;
    }
    #pragma unroll
    for (int m=1;m<16;m<<=1){ s_ += __shfl_xor(s_,m); q_ += __shfl_xor(q_,m); }
    float mean = s_*(1.f/512.f), var = q_*(1.f/512.f)-mean*mean, rs = rsqrtf(var+1e-5f);
    #pragma unroll
    for (int i=0;i<8;i++){
      int c = seg*32 + i*4;
      uint2 uv;
      uv.x = pkbf((v[i].x-mean)*rs*lg[c  ]+lb[c  ], (v[i].y-mean)*rs*lg[c+1]+lb[c+1]);
      uv.y = pkbf((v[i].z-mean)*rs*lg[c+2]+lb[c+2], (v[i].w-mean)*rs*lg[c+3]+lb[c+3]);
      *reinterpret_cast<uint2*>(&As[row][c]) = uv;
    }
  }
  __syncthreads();
  const int wv = t>>6, lane = t&63;
  const int frow = lane&15, kgrp = (lane>>4)*8, rbase = (lane>>4)*4;
  int n0 = (blockIdx.y*4 + wv)*16;
  f32x4 acc = fz4();
  for (int k0=0;k0<K;k0+=32){
    bf16x8 af = *reinterpret_cast<const bf16x8*>(&As[frow][k0+kgrp]);
    bf16x8 bf_ = *reinterpret_cast<const bf16x8*>(Bt + (size_t)(n0+frow)*K + k0+kgrp);
    acc = MFMA(af,bf_,acc);
  }
  int col = n0 + frow;
  float bs = bias[col];
  #pragma unroll
  for (int r=0;r<4;r++){
    size_t row = (size_t)(r0 + rbase + r);
    float v = acc[r] + bs;
    v = v>0.f ? v : (__expf(v)-1.f);
    outb[row*N + col] = bfc(v);
  }
}

extern "C" void kernel_launch(void* const* d_in, const int* in_sizes, int n_in,
                              void* d_out, int out_size, void* d_ws, size_t ws_size,
                              hipStream_t stream)
{
  (void)in_sizes; (void)n_in; (void)out_size; (void)ws_size;
  const float* h      = (const float*)d_in[0];
  const float* e      = (const float*)d_in[1];
  const float* ln_h_g = (const float*)d_in[2];
  const float* ln_h_b = (const float*)d_in[3];
  const float* ln_e_g = (const float*)d_in[4];
  const float* ln_e_b = (const float*)d_in[5];
  const float* W_QKV  = (const float*)d_in[6];
  const float* b_QKV  = (const float*)d_in[7];
  const float* W_E    = (const float*)d_in[8];
  const float* b_E    = (const float*)d_in[9];
  const float* W_G    = (const float*)d_in[10];
  const float* b_G    = (const float*)d_in[11];
  const float* W_Oh   = (const float*)d_in[12];
  const float* b_Oh   = (const float*)d_in[13];
  const float* f_ln_h_g = (const float*)d_in[14];
  const float* f_ln_h_b = (const float*)d_in[15];
  const float* W_h1   = (const float*)d_in[16];
  const float* b_h1   = (const float*)d_in[17];
  const float* W_h2   = (const float*)d_in[18];
  const float* b_h2   = (const float*)d_in[19];
  const float* W_Oe   = (const float*)d_in[20];
  const float* b_Oe   = (const float*)d_in[21];
  const float* f_ln_e_g = (const float*)d_in[22];
  const float* f_ln_e_b = (const float*)d_in[23];
  const float* W_e1   = (const float*)d_in[24];
  const float* b_e1   = (const float*)d_in[25];
  const float* W_e2   = (const float*)d_in[26];
  const float* b_e2   = (const float*)d_in[27];

  float* out   = (float*)d_out;
  float* h_out = out;
  float* e_out = out + (size_t)4*512*512;

  char* w = (char*)d_ws;
  size_t off = 0;
  auto alloc = [&](size_t bytes)->char*{ char* p = w + off; off += (bytes + 255) & ~(size_t)255; return p; };
  u16t* hln   = (u16t*)alloc(2048ull*512*2);
  u16t* WtQKV = (u16t*)alloc(1536ull*512*2);
  u16t* WtOh  = (u16t*)alloc(512ull*512*2);
  u16t* WtH1  = (u16t*)alloc(1024ull*512*2);
  u16t* WtH2  = (u16t*)alloc(512ull*1024*2);
  u16t* Qb    = (u16t*)alloc(4ull*8*512*64*2);
  u16t* Kb    = (u16t*)alloc(4ull*8*512*64*2);
  u16t* Vt    = (u16t*)alloc(4ull*8*64*512*2);
  u16t* Vp    = (u16t*)alloc(4ull*2048*512*2);
  float* Sp   = (float*)alloc(4ull*512*8*4*4);
  float* Dp   = (float*)alloc(4ull*512*8*4*4);
  u16t* Va    = (u16t*)alloc(2048ull*512*2);
  float* h1   = (float*)alloc(2048ull*512*4);
  u16t* U     = (u16t*)alloc(2048ull*1024*2);

  kprep<<<1024, 256, 0, stream>>>(h, ln_h_g, ln_h_b, hln,
      W_QKV, WtQKV, W_Oh, WtOh, W_h1, WtH1, W_h2, WtH2);
  kqkv<<<128, 256, 0, stream>>>(hln, WtQKV, b_QKV, Qb, Kb, Vt);
  kattnF<<<dim3(32,4,4), 512, 0, stream>>>(e, ln_e_g, ln_e_b, W_E, b_E, W_G, b_G,
      Qb, Kb, Vt, W_Oe, b_Oe, f_ln_e_g, f_ln_e_b, W_e1, b_e1, W_e2, b_e2,
      Vp, Sp, Dp, e_out);
  kvfin<<<2048, 256, 0, stream>>>(Vp, Sp, Dp, Va);
  kgemmNS<<<dim3(128,8), 256, 0, stream>>>(Va, WtOh, b_Oh, h, h1, nullptr, 512, 512, 0);
  kgemmLN<<<dim3(128,16), 256, 0, stream>>>(h1, f_ln_h_g, f_ln_h_b, WtH1, b_h1, U, 1024, 512);
  kgemmNS<<<dim3(128,8), 256, 0, stream>>>(U, WtH2, b_h2, h1, h_out, nullptr, 512, 1024, 0);
}

// Round 15
// 330.042 us; speedup vs baseline: 1.1846x; 1.1846x over previous
//
#include <hip/hip_runtime.h>
#include <math.h>

typedef unsigned short u16t;
typedef unsigned int   u32t;
typedef __bf16 bf16x2 __attribute__((ext_vector_type(2)));
typedef __bf16 bf16x8 __attribute__((ext_vector_type(8)));
typedef float  f32x4  __attribute__((ext_vector_type(4)));

#define DEV static __device__ __forceinline__

DEV u16t bfc(float x){ __bf16 b = (__bf16)x; return __builtin_bit_cast(u16t, b); }
DEV u32t pkbf(float a, float b){ bf16x2 v = {(__bf16)a, (__bf16)b}; return __builtin_bit_cast(u32t, v); }
DEV float flc(u16t u){ return __uint_as_float(((u32t)u)<<16); }
DEV u32t pk2(u16t a, u16t b){ return (u32t)a | ((u32t)b<<16); }
DEV f32x4 fz4(){ f32x4 z = {0.f,0.f,0.f,0.f}; return z; }
DEV bf16x8 bz8(){ uint4 z = make_uint4(0u,0u,0u,0u); return __builtin_bit_cast(bf16x8, z); }
DEV f32x4 MFMA(bf16x8 a, bf16x8 b, f32x4 c){ return __builtin_amdgcn_mfma_f32_16x16x32_bf16(a,b,c,0,0,0); }

// ---------------- prep: LN(h) (blocks 0..511) + tiled coalesced weight transposes (512..1023) ----------------
__global__ __launch_bounds__(256) void kprep(
    const float* __restrict__ h, const float* __restrict__ g, const float* __restrict__ bb, u16t* __restrict__ hln,
    const float* __restrict__ A, u16t* __restrict__ oA,
    const float* __restrict__ B, u16t* __restrict__ oB,
    const float* __restrict__ C, u16t* __restrict__ oC,
    const float* __restrict__ D, u16t* __restrict__ oD)
{
  if (blockIdx.x < 512){
    int wv = threadIdx.x >> 6, lane = threadIdx.x & 63;
    int row = blockIdx.x*4 + wv;
    const float4* rp = reinterpret_cast<const float4*>(h + (size_t)row*512);
    float4 v0 = rp[lane], v1 = rp[lane+64];
    float s = v0.x+v0.y+v0.z+v0.w + v1.x+v1.y+v1.z+v1.w;
    float q = v0.x*v0.x+v0.y*v0.y+v0.z*v0.z+v0.w*v0.w + v1.x*v1.x+v1.y*v1.y+v1.z*v1.z+v1.w*v1.w;
    #pragma unroll
    for (int m=1;m<64;m<<=1){ s += __shfl_xor(s,m); q += __shfl_xor(q,m); }
    float mean = s*(1.f/512.f), var = q*(1.f/512.f)-mean*mean, rs = rsqrtf(var+1e-5f);
    const float4* gp = reinterpret_cast<const float4*>(g);
    const float4* bp = reinterpret_cast<const float4*>(bb);
    float4 g0=gp[lane], g1=gp[lane+64], b0=bp[lane], b1=bp[lane+64];
    u16t* op = hln + (size_t)row*512;
    uint2 o0, o1;
    o0.x = pkbf((v0.x-mean)*rs*g0.x+b0.x, (v0.y-mean)*rs*g0.y+b0.y);
    o0.y = pkbf((v0.z-mean)*rs*g0.z+b0.z, (v0.w-mean)*rs*g0.w+b0.w);
    o1.x = pkbf((v1.x-mean)*rs*g1.x+b1.x, (v1.y-mean)*rs*g1.y+b1.y);
    o1.y = pkbf((v1.z-mean)*rs*g1.z+b1.z, (v1.w-mean)*rs*g1.w+b1.w);
    reinterpret_cast<uint2*>(op)[lane]    = o0;
    reinterpret_cast<uint2*>(op)[lane+64] = o1;
    return;
  }
  __shared__ u16t Ts[64][68];
  int bid = blockIdx.x - 512;
  const float* src; u16t* dst; int K, N, perm = 0;
  if      (bid < 192){             src=A;  dst=oA;  K=512;  N=1536; }
  else if (bid < 256){ bid-=192;   src=B;  dst=oB;  K=512;  N=512;  perm=1; }
  else if (bid < 384){ bid-=256;   src=C;  dst=oC;  K=512;  N=1024; }
  else {               bid-=384;   src=D;  dst=oD;  K=1024; N=512;  }
  const int ntn = N>>6;
  const int kt = bid / ntn, nt = bid % ntn;
  const int k0 = kt*64, n0 = nt*64;
  const int t = threadIdx.x, c = t&63, rr = t>>6;
  #pragma unroll
  for (int i=0;i<16;i++){
    int j = rr + i*4;
    int ks = perm ? (j*8 + kt) : (k0 + j);
    Ts[j][c] = bfc(src[(size_t)ks*N + n0 + c]);
  }
  __syncthreads();
  #pragma unroll
  for (int i=0;i<16;i++){
    int n = rr + i*4;
    dst[(size_t)(n0+n)*K + k0 + c] = Ts[c][n];
  }
}

// ---------------- QKV GEMM, N-split: grid (128, 6). slices 0-1 Q, 2-3 K, 4-5 V (256 cols each) ----------------
__global__ __launch_bounds__(256) void kqkv(const u16t* __restrict__ hln, const u16t* __restrict__ Wt,
    const float* __restrict__ bias, u16t* __restrict__ Qb, u16t* __restrict__ Kb, u16t* __restrict__ Vt)
{
  __shared__ __align__(16) u16t As[16][520];
  __shared__ __align__(16) u16t Cs[16][264];
  const int r0 = blockIdx.x*16, s = blockIdx.y, t = threadIdx.x;
  const int b8 = (r0 >> 9) * 8, pos0 = r0 & 511;
  {
    int row = t>>4, seg = t&15;
    const uint4* src = reinterpret_cast<const uint4*>(hln + (size_t)(r0+row)*512 + seg*32);
    uint4* dst = reinterpret_cast<uint4*>(&As[row][seg*32]);
    dst[0]=src[0]; dst[1]=src[1]; dst[2]=src[2]; dst[3]=src[3];
  }
  __syncthreads();
  const int wv = t>>6, lane = t&63;
  const int frow = lane&15, kgrp = (lane>>4)*8, rbase = (lane>>4)*4;
  const int isV = (s >= 4);
  for (int nt=0; nt<4; nt++){
    int nl0 = (wv*4+nt)*16;            // local col base within slice
    int n0g = s*256 + nl0;             // global col
    f32x4 acc = fz4();
    for (int k0=0;k0<512;k0+=32){
      bf16x8 af = *reinterpret_cast<const bf16x8*>(&As[frow][k0+kgrp]);
      bf16x8 bf_ = *reinterpret_cast<const bf16x8*>(Wt + (size_t)(n0g+frow)*512 + k0+kgrp);
      acc = MFMA(af,bf_,acc);
    }
    int col = n0g + frow;
    float bs = bias[col];
    if (!isV){
      #pragma unroll
      for (int r=0;r<4;r++) Cs[rbase+r][nl0+frow] = bfc(acc[r]+bs);
    } else {
      int cc = col - 1024, dv = cc>>3, hq = cc&7;
      ushort4 u4 = make_ushort4(bfc(acc[0]+bs), bfc(acc[1]+bs), bfc(acc[2]+bs), bfc(acc[3]+bs));
      *reinterpret_cast<ushort4*>(Vt + ((size_t)(b8+hq)*64 + dv)*512 + pos0 + rbase) = u4;
    }
  }
  if (isV) return;
  __syncthreads();
  {
    // transpose epilogue for this slice: 256 thr; hq = t>>5, lq = (t&31)>>1, dh = t&1
    int hq = t>>5, rem = t&31, lq = rem>>1, dh = rem&1;
    int d0s = (s&1)*32;                // head-dim offset of this slice
    int pos = pos0 + lq;
    u16t* dst = ((s>=2) ? Kb : Qb) + ((size_t)(b8+hq)*512 + pos)*64 + d0s + dh*16;
    #pragma unroll
    for (int v2=0; v2<2; v2++){
      int dl = dh*16 + v2*8;           // local d within slice (0..31)
      uint4 u;
      u.x = pk2(Cs[lq][(dl+0)*8+hq], Cs[lq][(dl+1)*8+hq]);
      u.y = pk2(Cs[lq][(dl+2)*8+hq], Cs[lq][(dl+3)*8+hq]);
      u.z = pk2(Cs[lq][(dl+4)*8+hq], Cs[lq][(dl+5)*8+hq]);
      u.w = pk2(Cs[lq][(dl+6)*8+hq], Cs[lq][(dl+7)*8+hq]);
      reinterpret_cast<uint4*>(dst)[v2] = u;
    }
  }
}

// ---------------- fused e-stream (proven 259us config) + folded PV ----------------
// grid (32 lblk, 4 chunk, 4 b) = 512 blocks = 2/CU. wave wv: head wv (QK+PV, 16 l-rows) + l-rows {2wv,2wv+1}.
__global__ __launch_bounds__(512,4) void kattnF(
    const float* __restrict__ e, const float* __restrict__ lng, const float* __restrict__ lnb,
    const float* __restrict__ WE, const float* __restrict__ bE,
    const float* __restrict__ WG, const float* __restrict__ bG,
    const u16t* __restrict__ Qb, const u16t* __restrict__ Kb, const u16t* __restrict__ Vt,
    const float* __restrict__ WOe, const float* __restrict__ bOe,
    const float* __restrict__ flg, const float* __restrict__ flb,
    const float* __restrict__ We1, const float* __restrict__ be1,
    const float* __restrict__ We2, const float* __restrict__ be2,
    u16t* __restrict__ Vp, float* __restrict__ Sp, float* __restrict__ Dp,
    float* __restrict__ eout)
{
  __shared__ __align__(16) u16t Eln[256][72];
  __shared__ u16t EGb[256][18];
  __shared__ __align__(16) u16t Hl[256][8];
  __shared__ __align__(16) u16t Pgs[16][8][16];
  __shared__ __align__(16) u16t WEGt[16][72];
  __shared__ __align__(16) u16t We1t[64][72];
  __shared__ __align__(16) u16t We2t[64][72];
  __shared__ __align__(16) u16t WOeT[64][8];
  __shared__ float lgs[64], lbs[64], flgs[64], flbs[64], bOes[64], be1s[64], be2s[64];
  __shared__ float bEs[8], bGs[8];

  const int t = threadIdx.x;
  const int b = blockIdx.z, lblk = blockIdx.x, chunk = blockIdx.y;
  const int l0 = lblk*16, m0g = chunk*128, b8 = b*8;

  if (t < 64){
    lgs[t]=lng[t]; lbs[t]=lnb[t]; flgs[t]=flg[t]; flbs[t]=flb[t];
    bOes[t]=bOe[t]; be1s[t]=be1[t]; be2s[t]=be2[t];
  }
  if (t < 8){ bEs[t]=bE[t]; bGs[t]=bG[t]; }
  for (int i=t; i<1024; i+=512){
    int n = i>>6, k = i&63;
    WEGt[n][k] = bfc(n<8 ? WE[k*8+n] : WG[k*8+(n-8)]);
  }
  for (int i=t; i<4096; i+=512){
    int n=i>>6, k=i&63;
    We1t[n][k] = bfc(We1[k*64+n]);
    We2t[n][k] = bfc(We2[k*64+n]);
  }
  {
    int n=t>>3, hh=t&7;
    WOeT[n][hh] = bfc(WOe[hh*64+n]);
  }
  __syncthreads();

  const int wv = t>>6, lane = t&63;
  const int frow = lane&15, kgrp = (lane>>4)*8, rbase = (lane>>4)*4;

  bf16x8 qf[2];
  #pragma unroll
  for (int kk=0;kk<2;kk++)
    qf[kk] = *reinterpret_cast<const bf16x8*>(Qb + ((size_t)(b8+wv)*512 + l0+frow)*64 + kk*32 + kgrp);

  float Ssum[4] = {0.f,0.f,0.f,0.f}, Dsum[4] = {0.f,0.f,0.f,0.f};
  f32x4 accV[4];
  #pragma unroll
  for (int d=0;d<4;d++) accV[d]=fz4();

  const float* ebs[2];
  #pragma unroll
  for (int ti=0; ti<2; ti++)
    ebs[ti] = e + ((size_t)((b*512 + l0 + 2*wv+ti)*512) + m0g + frow)*64 + rbase;

  float4 xr[2][4];
  #pragma unroll
  for (int ti=0; ti<2; ti++)
    #pragma unroll
    for (int nb=0; nb<4; nb++)
      xr[ti][nb] = *reinterpret_cast<const float4*>(ebs[ti] + nb*16);

  #pragma unroll 1
  for (int mt=0; mt<8; mt++){
    const int m0 = m0g + mt*16;
    // ---- P1: LN(e)
    #pragma unroll
    for (int ti=0; ti<2; ti++){
      const int T = 2*wv + ti;
      float s_=0.f, q_=0.f;
      #pragma unroll
      for (int nb=0; nb<4; nb++){
        float4 v = xr[ti][nb];
        s_ += v.x+v.y+v.z+v.w;
        q_ += v.x*v.x+v.y*v.y+v.z*v.z+v.w*v.w;
      }
      s_ += __shfl_xor(s_,16); q_ += __shfl_xor(q_,16);
      s_ += __shfl_xor(s_,32); q_ += __shfl_xor(q_,32);
      float mean = s_*(1.f/64.f), var = q_*(1.f/64.f)-mean*mean, rs = rsqrtf(var+1e-5f);
      #pragma unroll
      for (int nb=0; nb<4; nb++){
        int n = nb*16 + rbase;
        float4 v = xr[ti][nb];
        uint2 uv;
        uv.x = pkbf((v.x-mean)*rs*lgs[n  ]+lbs[n  ], (v.y-mean)*rs*lgs[n+1]+lbs[n+1]);
        uv.y = pkbf((v.z-mean)*rs*lgs[n+2]+lbs[n+2], (v.w-mean)*rs*lgs[n+3]+lbs[n+3]);
        *reinterpret_cast<uint2*>(&Eln[T*16+frow][n]) = uv;
      }
    }
    // ---- P2: E||G
    #pragma unroll
    for (int ti=0; ti<2; ti++){
      int T = wv*2+ti;
      bf16x8 a0 = *reinterpret_cast<const bf16x8*>(&Eln[T*16+frow][kgrp]);
      bf16x8 a1 = *reinterpret_cast<const bf16x8*>(&Eln[T*16+frow][32+kgrp]);
      bf16x8 w0 = *reinterpret_cast<const bf16x8*>(&WEGt[frow][kgrp]);
      bf16x8 w1 = *reinterpret_cast<const bf16x8*>(&WEGt[frow][32+kgrp]);
      f32x4 acc = fz4(); acc = MFMA(a0,w0,acc); acc = MFMA(a1,w1,acc);
      #pragma unroll
      for (int r=0;r<4;r++) EGb[T*16+rbase+r][frow] = bfc(acc[r]);
    }
    __syncthreads();
    // ---- P3: QK^T + combine
    {
      const u16t* kb = Kb + ((size_t)(b8+wv)*512 + m0)*64 + frow*64 + kgrp;
      bf16x8 kf0 = *reinterpret_cast<const bf16x8*>(kb);
      bf16x8 kf1 = *reinterpret_cast<const bf16x8*>(kb + 32);
      f32x4 aq = fz4();
      aq = MFMA(qf[0], kf0, aq);
      aq = MFMA(qf[1], kf1, aq);
      #pragma unroll
      for (int r=0;r<4;r++){
        int lrow = rbase + r;
        int eidx = lrow*16 + frow;
        float ah = aq[r]*0.125f;
        ah = fminf(fmaxf(ah, -5.f), 5.f);
        float Ev = flc(EGb[eidx][wv])   + bEs[wv];
        float Gv = flc(EGb[eidx][8+wv]) + bGs[wv];
        float Hv = ah + Ev;
        float P = __expf(Hv);
        float g = 1.f/(1.f+__expf(-Gv));
        Ssum[r] += P; Dsum[r] += g;
        Hl[eidx][wv] = bfc(Hv);
        Pgs[lrow][wv][frow] = bfc(P*g);
      }
    }
    // ---- PV
    {
      bf16x8 pa = (kgrp<16)
        ? *reinterpret_cast<const bf16x8*>(&Pgs[frow][wv][kgrp]) : bz8();
      #pragma unroll
      for (int db=0; db<4; db++){
        bf16x8 vb = (kgrp<16)
          ? *reinterpret_cast<const bf16x8*>(Vt + ((size_t)(b8+wv)*64 + db*16+frow)*512 + m0 + kgrp)
          : bz8();
        accV[db] = MFMA(pa, vb, accV[db]);
      }
    }
    __syncthreads();
    // ---- P5: edge FFN
    #pragma unroll
    for (int ti=0; ti<2; ti++){
      const int T = 2*wv + ti;
      bf16x8 hf_ = bz8();
      if (kgrp==0) hf_ = *reinterpret_cast<const bf16x8*>(&Hl[T*16+frow][0]);
      f32x4 e1a[4];
      #pragma unroll
      for (int nb=0; nb<4; nb++){
        bf16x8 wf = bz8();
        if (kgrp==0) wf = *reinterpret_cast<const bf16x8*>(&WOeT[nb*16][0] + frow*8);
        e1a[nb] = MFMA(wf, hf_, fz4());
      }
      #pragma unroll
      for (int nb=0; nb<4; nb++){
        int n = nb*16 + rbase;
        e1a[nb][0] += bOes[n  ] + xr[ti][nb].x;
        e1a[nb][1] += bOes[n+1] + xr[ti][nb].y;
        e1a[nb][2] += bOes[n+2] + xr[ti][nb].z;
        e1a[nb][3] += bOes[n+3] + xr[ti][nb].w;
      }
      if (mt+1 < 8){
        #pragma unroll
        for (int nb=0; nb<4; nb++)
          xr[ti][nb] = *reinterpret_cast<const float4*>(ebs[ti] + (size_t)(mt+1)*1024 + nb*16);
      }
      {
        float s_=0.f, q_=0.f;
        #pragma unroll
        for (int nb=0; nb<4; nb++){
          #pragma unroll
          for (int r=0;r<4;r++){ float v = e1a[nb][r]; s_ += v; q_ += v*v; }
        }
        s_ += __shfl_xor(s_,16); q_ += __shfl_xor(q_,16);
        s_ += __shfl_xor(s_,32); q_ += __shfl_xor(q_,32);
        float mean = s_*(1.f/64.f), var = q_*(1.f/64.f)-mean*mean, rs = rsqrtf(var+1e-5f);
        #pragma unroll
        for (int nb=0; nb<4; nb++){
          int n = nb*16 + rbase;
          uint2 uv;
          uv.x = pkbf((e1a[nb][0]-mean)*rs*flgs[n  ]+flbs[n  ], (e1a[nb][1]-mean)*rs*flgs[n+1]+flbs[n+1]);
          uv.y = pkbf((e1a[nb][2]-mean)*rs*flgs[n+2]+flbs[n+2], (e1a[nb][3]-mean)*rs*flgs[n+3]+flbs[n+3]);
          *reinterpret_cast<uint2*>(&Eln[T*16+frow][n]) = uv;
        }
      }
      {
        bf16x8 x0 = *reinterpret_cast<const bf16x8*>(&Eln[T*16+frow][kgrp]);
        bf16x8 x1 = *reinterpret_cast<const bf16x8*>(&Eln[T*16+frow][32+kgrp]);
        f32x4 acc1[4];
        #pragma unroll
        for (int nb=0;nb<4;nb++){
          bf16x8 w0 = *reinterpret_cast<const bf16x8*>(&We1t[nb*16+frow][kgrp]);
          bf16x8 w1 = *reinterpret_cast<const bf16x8*>(&We1t[nb*16+frow][32+kgrp]);
          f32x4 a_ = fz4(); a_ = MFMA(w0,x0,a_); a_ = MFMA(w1,x1,a_);
          acc1[nb] = a_;
        }
        #pragma unroll
        for (int nb=0;nb<4;nb++){
          int n = nb*16 + rbase;
          float v0 = acc1[nb][0] + be1s[n  ]; v0 = v0>0.f ? v0 : (__expf(v0)-1.f);
          float v1 = acc1[nb][1] + be1s[n+1]; v1 = v1>0.f ? v1 : (__expf(v1)-1.f);
          float v2 = acc1[nb][2] + be1s[n+2]; v2 = v2>0.f ? v2 : (__expf(v2)-1.f);
          float v3 = acc1[nb][3] + be1s[n+3]; v3 = v3>0.f ? v3 : (__expf(v3)-1.f);
          uint2 uv;
          uv.x = pkbf(v0, v1);
          uv.y = pkbf(v2, v3);
          *reinterpret_cast<uint2*>(&Eln[T*16+frow][n]) = uv;
        }
      }
      {
        bf16x8 x0 = *reinterpret_cast<const bf16x8*>(&Eln[T*16+frow][kgrp]);
        bf16x8 x1 = *reinterpret_cast<const bf16x8*>(&Eln[T*16+frow][32+kgrp]);
        float* eob = eout + ((size_t)((b*512 + l0 + T)*512) + m0 + frow)*64 + rbase;
        #pragma unroll
        for (int nb=0;nb<4;nb++){
          bf16x8 w0 = *reinterpret_cast<const bf16x8*>(&We2t[nb*16+frow][kgrp]);
          bf16x8 w1 = *reinterpret_cast<const bf16x8*>(&We2t[nb*16+frow][32+kgrp]);
          f32x4 a_ = fz4(); a_ = MFMA(w0,x0,a_); a_ = MFMA(w1,x1,a_);
          int n = nb*16 + rbase;
          float4 o;
          o.x = a_[0] + be2s[n  ] + e1a[nb][0];
          o.y = a_[1] + be2s[n+1] + e1a[nb][1];
          o.z = a_[2] + be2s[n+2] + e1a[nb][2];
          o.w = a_[3] + be2s[n+3] + e1a[nb][3];
          *reinterpret_cast<float4*>(eob + nb*16) = o;
        }
      }
    }
  }

  #pragma unroll
  for (int r=0;r<4;r++){
    float sv = Ssum[r], dv = Dsum[r];
    #pragma unroll
    for (int msk=1; msk<16; msk<<=1){ sv += __shfl_xor(sv, msk); dv += __shfl_xor(dv, msk); }
    int lrow = rbase + r;
    if (frow == 0){
      size_t idx = ((size_t)(b*512 + l0 + lrow)*8 + wv)*4 + chunk;
      Sp[idx] = sv; Dp[idx] = dv;
    }
  }
  __syncthreads();
  float* Vo = reinterpret_cast<float*>(&Eln[0][0]);   // [16][512] f32
  #pragma unroll
  for (int db=0; db<4; db++){
    #pragma unroll
    for (int r=0;r<4;r++)
      Vo[(size_t)(rbase+r)*512 + wv*64 + db*16 + frow] = accV[db][r];
  }
  __syncthreads();
  {
    int row = t>>5, i = t&31;
    u16t* vpb = Vp + ((size_t)(chunk*2048 + b*512 + l0 + row))*512 + i*16;
    const float* vsrc = &Vo[(size_t)row*512 + i*16];
    uint4 o0, o1;
    o0.x = pkbf(vsrc[0],  vsrc[1]);  o0.y = pkbf(vsrc[2],  vsrc[3]);
    o0.z = pkbf(vsrc[4],  vsrc[5]);  o0.w = pkbf(vsrc[6],  vsrc[7]);
    o1.x = pkbf(vsrc[8],  vsrc[9]);  o1.y = pkbf(vsrc[10], vsrc[11]);
    o1.z = pkbf(vsrc[12], vsrc[13]); o1.w = pkbf(vsrc[14], vsrc[15]);
    reinterpret_cast<uint4*>(vpb)[0] = o0;
    reinterpret_cast<uint4*>(vpb)[1] = o1;
  }
}

// ---------------- finalize: Va = (sum_chunks Vp) * log1p(deg)/S ----------------
__global__ __launch_bounds__(256) void kvfin(const u16t* __restrict__ Vp,
    const float* __restrict__ Sp, const float* __restrict__ Dp, u16t* __restrict__ Va)
{
  const int row = blockIdx.x;
  const int t = threadIdx.x;
  __shared__ float scl[8];
  if (t < 8){
    const float* sp = Sp + ((size_t)row*8 + t)*4;
    const float* dp = Dp + ((size_t)row*8 + t)*4;
    float S = sp[0]+sp[1]+sp[2]+sp[3];
    float D = dp[0]+dp[1]+dp[2]+dp[3];
    scl[t] = log1pf(D)/S;
  }
  __syncthreads();
  int c = t*2;
  float v0=0.f, v1=0.f;
  #pragma unroll
  for (int ch=0; ch<4; ch++){
    u32t u = *reinterpret_cast<const u32t*>(Vp + ((size_t)(ch*2048 + row))*512 + c);
    v0 += flc((u16t)(u & 0xffffu));
    v1 += flc((u16t)(u >> 16));
  }
  float s = scl[c>>6];
  *reinterpret_cast<u32t*>(Va + (size_t)row*512 + c) = pkbf(v0*s, v1*s);
}

// ---------------- LayerNorm over 512-wide rows -> bf16 ----------------
__global__ __launch_bounds__(256) void kln(const float* __restrict__ in, const float* __restrict__ g,
                                           const float* __restrict__ b, u16t* __restrict__ out){
  int wv = threadIdx.x >> 6, lane = threadIdx.x & 63;
  int row = blockIdx.x*4 + wv;
  const float4* rp = reinterpret_cast<const float4*>(in + (size_t)row*512);
  float4 v0 = rp[lane], v1 = rp[lane+64];
  float s = v0.x+v0.y+v0.z+v0.w + v1.x+v1.y+v1.z+v1.w;
  float q = v0.x*v0.x+v0.y*v0.y+v0.z*v0.z+v0.w*v0.w + v1.x*v1.x+v1.y*v1.y+v1.z*v1.z+v1.w*v1.w;
  #pragma unroll
  for (int m=1;m<64;m<<=1){ s += __shfl_xor(s,m); q += __shfl_xor(q,m); }
  float mean = s*(1.f/512.f), var = q*(1.f/512.f)-mean*mean, rs = rsqrtf(var+1e-5f);
  const float4* gp = reinterpret_cast<const float4*>(g);
  const float4* bp = reinterpret_cast<const float4*>(b);
  float4 g0=gp[lane], g1=gp[lane+64], b0=bp[lane], b1=bp[lane+64];
  u16t* op = out + (size_t)row*512;
  uint2 o0, o1;
  o0.x = pkbf((v0.x-mean)*rs*g0.x+b0.x, (v0.y-mean)*rs*g0.y+b0.y);
  o0.y = pkbf((v0.z-mean)*rs*g0.z+b0.z, (v0.w-mean)*rs*g0.w+b0.w);
  o1.x = pkbf((v1.x-mean)*rs*g1.x+b1.x, (v1.y-mean)*rs*g1.y+b1.y);
  o1.y = pkbf((v1.z-mean)*rs*g1.z+b1.z, (v1.w-mean)*rs*g1.w+b1.w);
  reinterpret_cast<uint2*>(op)[lane]    = o0;
  reinterpret_cast<uint2*>(op)[lane+64] = o1;
}

// ---------------- N-split GEMM ----------------
__global__ __launch_bounds__(256) void kgemmNS(const u16t* __restrict__ A, const u16t* __restrict__ Bt,
    const float* __restrict__ bias, const float* __restrict__ res,
    float* __restrict__ outf, u16t* __restrict__ outb, int N, int K, int do_elu)
{
  __shared__ __align__(16) u16t As[16][1032];
  const int r0 = blockIdx.x*16, t = threadIdx.x;
  {
    int row = t>>4, seg = t&15, cnt = K>>4;
    const uint4* src = reinterpret_cast<const uint4*>(A + (size_t)(r0+row)*K + seg*cnt);
    uint4* dst = reinterpret_cast<uint4*>(&As[row][seg*cnt]);
    for (int i=0;i<(cnt>>3);i++) dst[i] = src[i];
  }
  __syncthreads();
  const int wv = t>>6, lane = t&63;
  const int frow = lane&15, kgrp = (lane>>4)*8, rbase = (lane>>4)*4;
  int n0 = (blockIdx.y*4 + wv)*16;
  f32x4 acc = fz4();
  for (int k0=0;k0<K;k0+=32){
    bf16x8 af = *reinterpret_cast<const bf16x8*>(&As[frow][k0+kgrp]);
    bf16x8 bf_ = *reinterpret_cast<const bf16x8*>(Bt + (size_t)(n0+frow)*K + k0+kgrp);
    acc = MFMA(af,bf_,acc);
  }
  int col = n0 + frow;
  float bs = bias[col];
  #pragma unroll
  for (int r=0;r<4;r++){
    size_t row = (size_t)(r0 + rbase + r);
    float v = acc[r] + bs;
    if (do_elu) v = v>0.f ? v : (__expf(v)-1.f);
    if (res)  v += res[row*N + col];
    if (outf) outf[row*N + col] = v;
    if (outb) outb[row*N + col] = bfc(v);
  }
}

extern "C" void kernel_launch(void* const* d_in, const int* in_sizes, int n_in,
                              void* d_out, int out_size, void* d_ws, size_t ws_size,
                              hipStream_t stream)
{
  (void)in_sizes; (void)n_in; (void)out_size; (void)ws_size;
  const float* h      = (const float*)d_in[0];
  const float* e      = (const float*)d_in[1];
  const float* ln_h_g = (const float*)d_in[2];
  const float* ln_h_b = (const float*)d_in[3];
  const float* ln_e_g = (const float*)d_in[4];
  const float* ln_e_b = (const float*)d_in[5];
  const float* W_QKV  = (const float*)d_in[6];
  const float* b_QKV  = (const float*)d_in[7];
  const float* W_E    = (const float*)d_in[8];
  const float* b_E    = (const float*)d_in[9];
  const float* W_G    = (const float*)d_in[10];
  const float* b_G    = (const float*)d_in[11];
  const float* W_Oh   = (const float*)d_in[12];
  const float* b_Oh   = (const float*)d_in[13];
  const float* f_ln_h_g = (const float*)d_in[14];
  const float* f_ln_h_b = (const float*)d_in[15];
  const float* W_h1   = (const float*)d_in[16];
  const float* b_h1   = (const float*)d_in[17];
  const float* W_h2   = (const float*)d_in[18];
  const float* b_h2   = (const float*)d_in[19];
  const float* W_Oe   = (const float*)d_in[20];
  const float* b_Oe   = (const float*)d_in[21];
  const float* f_ln_e_g = (const float*)d_in[22];
  const float* f_ln_e_b = (const float*)d_in[23];
  const float* W_e1   = (const float*)d_in[24];
  const float* b_e1   = (const float*)d_in[25];
  const float* W_e2   = (const float*)d_in[26];
  const float* b_e2   = (const float*)d_in[27];

  float* out   = (float*)d_out;
  float* h_out = out;
  float* e_out = out + (size_t)4*512*512;

  char* w = (char*)d_ws;
  size_t off = 0;
  auto alloc = [&](size_t bytes)->char*{ char* p = w + off; off += (bytes + 255) & ~(size_t)255; return p; };
  u16t* hln   = (u16t*)alloc(2048ull*512*2);
  u16t* WtQKV = (u16t*)alloc(1536ull*512*2);
  u16t* WtOh  = (u16t*)alloc(512ull*512*2);
  u16t* WtH1  = (u16t*)alloc(1024ull*512*2);
  u16t* WtH2  = (u16t*)alloc(512ull*1024*2);
  u16t* Qb    = (u16t*)alloc(4ull*8*512*64*2);
  u16t* Kb    = (u16t*)alloc(4ull*8*512*64*2);
  u16t* Vt    = (u16t*)alloc(4ull*8*64*512*2);
  u16t* Vp    = (u16t*)alloc(4ull*2048*512*2);
  float* Sp   = (float*)alloc(4ull*512*8*4*4);
  float* Dp   = (float*)alloc(4ull*512*8*4*4);
  u16t* Va    = (u16t*)alloc(2048ull*512*2);
  float* h1   = (float*)alloc(2048ull*512*4);
  u16t* hfb   = (u16t*)alloc(2048ull*512*2);
  u16t* U     = (u16t*)alloc(2048ull*1024*2);

  kprep<<<1024, 256, 0, stream>>>(h, ln_h_g, ln_h_b, hln,
      W_QKV, WtQKV, W_Oh, WtOh, W_h1, WtH1, W_h2, WtH2);
  kqkv<<<dim3(128,6), 256, 0, stream>>>(hln, WtQKV, b_QKV, Qb, Kb, Vt);
  kattnF<<<dim3(32,4,4), 512, 0, stream>>>(e, ln_e_g, ln_e_b, W_E, b_E, W_G, b_G,
      Qb, Kb, Vt, W_Oe, b_Oe, f_ln_e_g, f_ln_e_b, W_e1, b_e1, W_e2, b_e2,
      Vp, Sp, Dp, e_out);
  kvfin<<<2048, 256, 0, stream>>>(Vp, Sp, Dp, Va);
  kgemmNS<<<dim3(128,8), 256, 0, stream>>>(Va, WtOh, b_Oh, h, h1, nullptr, 512, 512, 0);
  kln<<<512, 256, 0, stream>>>(h1, f_ln_h_g, f_ln_h_b, hfb);
  kgemmNS<<<dim3(128,16), 256, 0, stream>>>(hfb, WtH1, b_h1, nullptr, nullptr, U, 1024, 512, 1);
  kgemmNS<<<dim3(128,8), 256, 0, stream>>>(U, WtH2, b_h2, h1, h_out, nullptr, 512, 1024, 0);
}

// Round 16
// 326.787 us; speedup vs baseline: 1.1964x; 1.0100x over previous
//
#include <hip/hip_runtime.h>
#include <math.h>

typedef unsigned short u16t;
typedef unsigned int   u32t;
typedef __bf16 bf16x2 __attribute__((ext_vector_type(2)));
typedef __bf16 bf16x8 __attribute__((ext_vector_type(8)));
typedef float  f32x4  __attribute__((ext_vector_type(4)));

#define DEV static __device__ __forceinline__

DEV u16t bfc(float x){ __bf16 b = (__bf16)x; return __builtin_bit_cast(u16t, b); }
DEV u32t pkbf(float a, float b){ bf16x2 v = {(__bf16)a, (__bf16)b}; return __builtin_bit_cast(u32t, v); }
DEV float flc(u16t u){ return __uint_as_float(((u32t)u)<<16); }
DEV u32t pk2(u16t a, u16t b){ return (u32t)a | ((u32t)b<<16); }
DEV f32x4 fz4(){ f32x4 z = {0.f,0.f,0.f,0.f}; return z; }
DEV bf16x8 bz8(){ uint4 z = make_uint4(0u,0u,0u,0u); return __builtin_bit_cast(bf16x8, z); }
DEV f32x4 MFMA(bf16x8 a, bf16x8 b, f32x4 c){ return __builtin_amdgcn_mfma_f32_16x16x32_bf16(a,b,c,0,0,0); }

// ---------------- prep: LN(h) (blocks 0..511) + tiled coalesced weight transposes (512..1023) ----------------
__global__ __launch_bounds__(256) void kprep(
    const float* __restrict__ h, const float* __restrict__ g, const float* __restrict__ bb, u16t* __restrict__ hln,
    const float* __restrict__ A, u16t* __restrict__ oA,
    const float* __restrict__ B, u16t* __restrict__ oB,
    const float* __restrict__ C, u16t* __restrict__ oC,
    const float* __restrict__ D, u16t* __restrict__ oD)
{
  if (blockIdx.x < 512){
    int wv = threadIdx.x >> 6, lane = threadIdx.x & 63;
    int row = blockIdx.x*4 + wv;
    const float4* rp = reinterpret_cast<const float4*>(h + (size_t)row*512);
    float4 v0 = rp[lane], v1 = rp[lane+64];
    float s = v0.x+v0.y+v0.z+v0.w + v1.x+v1.y+v1.z+v1.w;
    float q = v0.x*v0.x+v0.y*v0.y+v0.z*v0.z+v0.w*v0.w + v1.x*v1.x+v1.y*v1.y+v1.z*v1.z+v1.w*v1.w;
    #pragma unroll
    for (int m=1;m<64;m<<=1){ s += __shfl_xor(s,m); q += __shfl_xor(q,m); }
    float mean = s*(1.f/512.f), var = q*(1.f/512.f)-mean*mean, rs = rsqrtf(var+1e-5f);
    const float4* gp = reinterpret_cast<const float4*>(g);
    const float4* bp = reinterpret_cast<const float4*>(bb);
    float4 g0=gp[lane], g1=gp[lane+64], b0=bp[lane], b1=bp[lane+64];
    u16t* op = hln + (size_t)row*512;
    uint2 o0, o1;
    o0.x = pkbf((v0.x-mean)*rs*g0.x+b0.x, (v0.y-mean)*rs*g0.y+b0.y);
    o0.y = pkbf((v0.z-mean)*rs*g0.z+b0.z, (v0.w-mean)*rs*g0.w+b0.w);
    o1.x = pkbf((v1.x-mean)*rs*g1.x+b1.x, (v1.y-mean)*rs*g1.y+b1.y);
    o1.y = pkbf((v1.z-mean)*rs*g1.z+b1.z, (v1.w-mean)*rs*g1.w+b1.w);
    reinterpret_cast<uint2*>(op)[lane]    = o0;
    reinterpret_cast<uint2*>(op)[lane+64] = o1;
    return;
  }
  __shared__ u16t Ts[64][68];
  int bid = blockIdx.x - 512;
  const float* src; u16t* dst; int K, N, perm = 0;
  if      (bid < 192){             src=A;  dst=oA;  K=512;  N=1536; }
  else if (bid < 256){ bid-=192;   src=B;  dst=oB;  K=512;  N=512;  perm=1; }
  else if (bid < 384){ bid-=256;   src=C;  dst=oC;  K=512;  N=1024; }
  else {               bid-=384;   src=D;  dst=oD;  K=1024; N=512;  }
  const int ntn = N>>6;
  const int kt = bid / ntn, nt = bid % ntn;
  const int k0 = kt*64, n0 = nt*64;
  const int t = threadIdx.x, c = t&63, rr = t>>6;
  #pragma unroll
  for (int i=0;i<16;i++){
    int j = rr + i*4;
    int ks = perm ? (j*8 + kt) : (k0 + j);
    Ts[j][c] = bfc(src[(size_t)ks*N + n0 + c]);
  }
  __syncthreads();
  #pragma unroll
  for (int i=0;i<16;i++){
    int n = rr + i*4;
    dst[(size_t)(n0+n)*K + k0 + c] = Ts[c][n];
  }
}

// ---------------- QKV GEMM, N-split: grid (128, 6). slices 0-1 Q, 2-3 K, 4-5 V (256 cols each) ----------------
__global__ __launch_bounds__(256) void kqkv(const u16t* __restrict__ hln, const u16t* __restrict__ Wt,
    const float* __restrict__ bias, u16t* __restrict__ Qb, u16t* __restrict__ Kb, u16t* __restrict__ Vt)
{
  __shared__ __align__(16) u16t As[16][520];
  __shared__ __align__(16) u16t Cs[16][264];
  const int r0 = blockIdx.x*16, s = blockIdx.y, t = threadIdx.x;
  const int b8 = (r0 >> 9) * 8, pos0 = r0 & 511;
  {
    int row = t>>4, seg = t&15;
    const uint4* src = reinterpret_cast<const uint4*>(hln + (size_t)(r0+row)*512 + seg*32);
    uint4* dst = reinterpret_cast<uint4*>(&As[row][seg*32]);
    dst[0]=src[0]; dst[1]=src[1]; dst[2]=src[2]; dst[3]=src[3];
  }
  __syncthreads();
  const int wv = t>>6, lane = t&63;
  const int frow = lane&15, kgrp = (lane>>4)*8, rbase = (lane>>4)*4;
  const int isV = (s >= 4);
  for (int nt=0; nt<4; nt++){
    int nl0 = (wv*4+nt)*16;
    int n0g = s*256 + nl0;
    f32x4 acc = fz4();
    for (int k0=0;k0<512;k0+=32){
      bf16x8 af = *reinterpret_cast<const bf16x8*>(&As[frow][k0+kgrp]);
      bf16x8 bf_ = *reinterpret_cast<const bf16x8*>(Wt + (size_t)(n0g+frow)*512 + k0+kgrp);
      acc = MFMA(af,bf_,acc);
    }
    int col = n0g + frow;
    float bs = bias[col];
    if (!isV){
      #pragma unroll
      for (int r=0;r<4;r++) Cs[rbase+r][nl0+frow] = bfc(acc[r]+bs);
    } else {
      int cc = col - 1024, dv = cc>>3, hq = cc&7;
      ushort4 u4 = make_ushort4(bfc(acc[0]+bs), bfc(acc[1]+bs), bfc(acc[2]+bs), bfc(acc[3]+bs));
      *reinterpret_cast<ushort4*>(Vt + ((size_t)(b8+hq)*64 + dv)*512 + pos0 + rbase) = u4;
    }
  }
  if (isV) return;
  __syncthreads();
  {
    int hq = t>>5, rem = t&31, lq = rem>>1, dh = rem&1;
    int d0s = (s&1)*32;
    int pos = pos0 + lq;
    u16t* dst = ((s>=2) ? Kb : Qb) + ((size_t)(b8+hq)*512 + pos)*64 + d0s + dh*16;
    #pragma unroll
    for (int v2=0; v2<2; v2++){
      int dl = dh*16 + v2*8;
      uint4 u;
      u.x = pk2(Cs[lq][(dl+0)*8+hq], Cs[lq][(dl+1)*8+hq]);
      u.y = pk2(Cs[lq][(dl+2)*8+hq], Cs[lq][(dl+3)*8+hq]);
      u.z = pk2(Cs[lq][(dl+4)*8+hq], Cs[lq][(dl+5)*8+hq]);
      u.w = pk2(Cs[lq][(dl+6)*8+hq], Cs[lq][(dl+7)*8+hq]);
      reinterpret_cast<uint4*>(dst)[v2] = u;
    }
  }
}

// ---------------- fused e-stream + folded PV; XCD-swizzled block mapping; batched e_out stores ----------------
// 512 blocks = 2/CU. swizzle: dispatch i -> work (i%8)*64 + i/8, so each XCD owns 2 whole (chunk,b) K/V groups.
__global__ __launch_bounds__(512,4) void kattnF(
    const float* __restrict__ e, const float* __restrict__ lng, const float* __restrict__ lnb,
    const float* __restrict__ WE, const float* __restrict__ bE,
    const float* __restrict__ WG, const float* __restrict__ bG,
    const u16t* __restrict__ Qb, const u16t* __restrict__ Kb, const u16t* __restrict__ Vt,
    const float* __restrict__ WOe, const float* __restrict__ bOe,
    const float* __restrict__ flg, const float* __restrict__ flb,
    const float* __restrict__ We1, const float* __restrict__ be1,
    const float* __restrict__ We2, const float* __restrict__ be2,
    u16t* __restrict__ Vp, float* __restrict__ Sp, float* __restrict__ Dp,
    float* __restrict__ eout)
{
  __shared__ __align__(16) u16t Eln[256][72];
  __shared__ u16t EGb[256][18];
  __shared__ __align__(16) u16t Hl[256][8];
  __shared__ __align__(16) u16t Pgs[16][8][16];
  __shared__ __align__(16) u16t WEGt[16][72];
  __shared__ __align__(16) u16t We1t[64][72];
  __shared__ __align__(16) u16t We2t[64][72];
  __shared__ __align__(16) u16t WOeT[64][8];
  __shared__ float lgs[64], lbs[64], flgs[64], flbs[64], bOes[64], be1s[64], be2s[64];
  __shared__ float bEs[8], bGs[8];

  const int t = threadIdx.x;
  const int lin = blockIdx.x + 32*(blockIdx.y + 4*blockIdx.z);
  const int swz = (lin & 7)*64 + (lin >> 3);
  const int lblk = swz & 31, chunk = (swz >> 5) & 3, b = swz >> 7;
  const int l0 = lblk*16, m0g = chunk*128, b8 = b*8;

  if (t < 64){
    lgs[t]=lng[t]; lbs[t]=lnb[t]; flgs[t]=flg[t]; flbs[t]=flb[t];
    bOes[t]=bOe[t]; be1s[t]=be1[t]; be2s[t]=be2[t];
  }
  if (t < 8){ bEs[t]=bE[t]; bGs[t]=bG[t]; }
  for (int i=t; i<1024; i+=512){
    int n = i>>6, k = i&63;
    WEGt[n][k] = bfc(n<8 ? WE[k*8+n] : WG[k*8+(n-8)]);
  }
  for (int i=t; i<4096; i+=512){
    int n=i>>6, k=i&63;
    We1t[n][k] = bfc(We1[k*64+n]);
    We2t[n][k] = bfc(We2[k*64+n]);
  }
  {
    int n=t>>3, hh=t&7;
    WOeT[n][hh] = bfc(WOe[hh*64+n]);
  }
  __syncthreads();

  const int wv = t>>6, lane = t&63;
  const int frow = lane&15, kgrp = (lane>>4)*8, rbase = (lane>>4)*4;

  bf16x8 qf[2];
  #pragma unroll
  for (int kk=0;kk<2;kk++)
    qf[kk] = *reinterpret_cast<const bf16x8*>(Qb + ((size_t)(b8+wv)*512 + l0+frow)*64 + kk*32 + kgrp);

  float Ssum[4] = {0.f,0.f,0.f,0.f}, Dsum[4] = {0.f,0.f,0.f,0.f};
  f32x4 accV[4];
  #pragma unroll
  for (int d=0;d<4;d++) accV[d]=fz4();

  const float* ebs[2];
  #pragma unroll
  for (int ti=0; ti<2; ti++)
    ebs[ti] = e + ((size_t)((b*512 + l0 + 2*wv+ti)*512) + m0g + frow)*64 + rbase;

  float4 xr[2][4];
  #pragma unroll
  for (int ti=0; ti<2; ti++)
    #pragma unroll
    for (int nb=0; nb<4; nb++)
      xr[ti][nb] = *reinterpret_cast<const float4*>(ebs[ti] + nb*16);

  #pragma unroll 1
  for (int mt=0; mt<8; mt++){
    const int m0 = m0g + mt*16;
    // ---- P1: LN(e)
    #pragma unroll
    for (int ti=0; ti<2; ti++){
      const int T = 2*wv + ti;
      float s_=0.f, q_=0.f;
      #pragma unroll
      for (int nb=0; nb<4; nb++){
        float4 v = xr[ti][nb];
        s_ += v.x+v.y+v.z+v.w;
        q_ += v.x*v.x+v.y*v.y+v.z*v.z+v.w*v.w;
      }
      s_ += __shfl_xor(s_,16); q_ += __shfl_xor(q_,16);
      s_ += __shfl_xor(s_,32); q_ += __shfl_xor(q_,32);
      float mean = s_*(1.f/64.f), var = q_*(1.f/64.f)-mean*mean, rs = rsqrtf(var+1e-5f);
      #pragma unroll
      for (int nb=0; nb<4; nb++){
        int n = nb*16 + rbase;
        float4 v = xr[ti][nb];
        uint2 uv;
        uv.x = pkbf((v.x-mean)*rs*lgs[n  ]+lbs[n  ], (v.y-mean)*rs*lgs[n+1]+lbs[n+1]);
        uv.y = pkbf((v.z-mean)*rs*lgs[n+2]+lbs[n+2], (v.w-mean)*rs*lgs[n+3]+lbs[n+3]);
        *reinterpret_cast<uint2*>(&Eln[T*16+frow][n]) = uv;
      }
    }
    // ---- P2: E||G
    #pragma unroll
    for (int ti=0; ti<2; ti++){
      int T = wv*2+ti;
      bf16x8 a0 = *reinterpret_cast<const bf16x8*>(&Eln[T*16+frow][kgrp]);
      bf16x8 a1 = *reinterpret_cast<const bf16x8*>(&Eln[T*16+frow][32+kgrp]);
      bf16x8 w0 = *reinterpret_cast<const bf16x8*>(&WEGt[frow][kgrp]);
      bf16x8 w1 = *reinterpret_cast<const bf16x8*>(&WEGt[frow][32+kgrp]);
      f32x4 acc = fz4(); acc = MFMA(a0,w0,acc); acc = MFMA(a1,w1,acc);
      #pragma unroll
      for (int r=0;r<4;r++) EGb[T*16+rbase+r][frow] = bfc(acc[r]);
    }
    __syncthreads();
    // ---- P3: QK^T + combine
    {
      const u16t* kb = Kb + ((size_t)(b8+wv)*512 + m0)*64 + frow*64 + kgrp;
      bf16x8 kf0 = *reinterpret_cast<const bf16x8*>(kb);
      bf16x8 kf1 = *reinterpret_cast<const bf16x8*>(kb + 32);
      f32x4 aq = fz4();
      aq = MFMA(qf[0], kf0, aq);
      aq = MFMA(qf[1], kf1, aq);
      #pragma unroll
      for (int r=0;r<4;r++){
        int lrow = rbase + r;
        int eidx = lrow*16 + frow;
        float ah = aq[r]*0.125f;
        ah = fminf(fmaxf(ah, -5.f), 5.f);
        float Ev = flc(EGb[eidx][wv])   + bEs[wv];
        float Gv = flc(EGb[eidx][8+wv]) + bGs[wv];
        float Hv = ah + Ev;
        float P = __expf(Hv);
        float g = 1.f/(1.f+__expf(-Gv));
        Ssum[r] += P; Dsum[r] += g;
        Hl[eidx][wv] = bfc(Hv);
        Pgs[lrow][wv][frow] = bfc(P*g);
      }
    }
    // ---- PV
    {
      bf16x8 pa = (kgrp<16)
        ? *reinterpret_cast<const bf16x8*>(&Pgs[frow][wv][kgrp]) : bz8();
      #pragma unroll
      for (int db=0; db<4; db++){
        bf16x8 vb = (kgrp<16)
          ? *reinterpret_cast<const bf16x8*>(Vt + ((size_t)(b8+wv)*64 + db*16+frow)*512 + m0 + kgrp)
          : bz8();
        accV[db] = MFMA(pa, vb, accV[db]);
      }
    }
    __syncthreads();
    // ---- P5: edge FFN
    #pragma unroll
    for (int ti=0; ti<2; ti++){
      const int T = 2*wv + ti;
      bf16x8 hf_ = bz8();
      if (kgrp==0) hf_ = *reinterpret_cast<const bf16x8*>(&Hl[T*16+frow][0]);
      f32x4 e1a[4];
      #pragma unroll
      for (int nb=0; nb<4; nb++){
        bf16x8 wf = bz8();
        if (kgrp==0) wf = *reinterpret_cast<const bf16x8*>(&WOeT[nb*16][0] + frow*8);
        e1a[nb] = MFMA(wf, hf_, fz4());
      }
      #pragma unroll
      for (int nb=0; nb<4; nb++){
        int n = nb*16 + rbase;
        e1a[nb][0] += bOes[n  ] + xr[ti][nb].x;
        e1a[nb][1] += bOes[n+1] + xr[ti][nb].y;
        e1a[nb][2] += bOes[n+2] + xr[ti][nb].z;
        e1a[nb][3] += bOes[n+3] + xr[ti][nb].w;
      }
      if (mt+1 < 8){
        #pragma unroll
        for (int nb=0; nb<4; nb++)
          xr[ti][nb] = *reinterpret_cast<const float4*>(ebs[ti] + (size_t)(mt+1)*1024 + nb*16);
      }
      {
        float s_=0.f, q_=0.f;
        #pragma unroll
        for (int nb=0; nb<4; nb++){
          #pragma unroll
          for (int r=0;r<4;r++){ float v = e1a[nb][r]; s_ += v; q_ += v*v; }
        }
        s_ += __shfl_xor(s_,16); q_ += __shfl_xor(q_,16);
        s_ += __shfl_xor(s_,32); q_ += __shfl_xor(q_,32);
        float mean = s_*(1.f/64.f), var = q_*(1.f/64.f)-mean*mean, rs = rsqrtf(var+1e-5f);
        #pragma unroll
        for (int nb=0; nb<4; nb++){
          int n = nb*16 + rbase;
          uint2 uv;
          uv.x = pkbf((e1a[nb][0]-mean)*rs*flgs[n  ]+flbs[n  ], (e1a[nb][1]-mean)*rs*flgs[n+1]+flbs[n+1]);
          uv.y = pkbf((e1a[nb][2]-mean)*rs*flgs[n+2]+flbs[n+2], (e1a[nb][3]-mean)*rs*flgs[n+3]+flbs[n+3]);
          *reinterpret_cast<uint2*>(&Eln[T*16+frow][n]) = uv;
        }
      }
      {
        bf16x8 x0 = *reinterpret_cast<const bf16x8*>(&Eln[T*16+frow][kgrp]);
        bf16x8 x1 = *reinterpret_cast<const bf16x8*>(&Eln[T*16+frow][32+kgrp]);
        f32x4 acc1[4];
        #pragma unroll
        for (int nb=0;nb<4;nb++){
          bf16x8 w0 = *reinterpret_cast<const bf16x8*>(&We1t[nb*16+frow][kgrp]);
          bf16x8 w1 = *reinterpret_cast<const bf16x8*>(&We1t[nb*16+frow][32+kgrp]);
          f32x4 a_ = fz4(); a_ = MFMA(w0,x0,a_); a_ = MFMA(w1,x1,a_);
          acc1[nb] = a_;
        }
        #pragma unroll
        for (int nb=0;nb<4;nb++){
          int n = nb*16 + rbase;
          float v0 = acc1[nb][0] + be1s[n  ]; v0 = v0>0.f ? v0 : (__expf(v0)-1.f);
          float v1 = acc1[nb][1] + be1s[n+1]; v1 = v1>0.f ? v1 : (__expf(v1)-1.f);
          float v2 = acc1[nb][2] + be1s[n+2]; v2 = v2>0.f ? v2 : (__expf(v2)-1.f);
          float v3 = acc1[nb][3] + be1s[n+3]; v3 = v3>0.f ? v3 : (__expf(v3)-1.f);
          uint2 uv;
          uv.x = pkbf(v0, v1);
          uv.y = pkbf(v2, v3);
          *reinterpret_cast<uint2*>(&Eln[T*16+frow][n]) = uv;
        }
      }
      // layer2: batch all 4 MFMAs, then 4 back-to-back stores (write-combine friendly)
      {
        bf16x8 x0 = *reinterpret_cast<const bf16x8*>(&Eln[T*16+frow][kgrp]);
        bf16x8 x1 = *reinterpret_cast<const bf16x8*>(&Eln[T*16+frow][32+kgrp]);
        f32x4 a2[4];
        #pragma unroll
        for (int nb=0;nb<4;nb++){
          bf16x8 w0 = *reinterpret_cast<const bf16x8*>(&We2t[nb*16+frow][kgrp]);
          bf16x8 w1 = *reinterpret_cast<const bf16x8*>(&We2t[nb*16+frow][32+kgrp]);
          f32x4 a_ = fz4(); a_ = MFMA(w0,x0,a_); a_ = MFMA(w1,x1,a_);
          int n = nb*16 + rbase;
          a2[nb][0] = a_[0] + be2s[n  ] + e1a[nb][0];
          a2[nb][1] = a_[1] + be2s[n+1] + e1a[nb][1];
          a2[nb][2] = a_[2] + be2s[n+2] + e1a[nb][2];
          a2[nb][3] = a_[3] + be2s[n+3] + e1a[nb][3];
        }
        float* eob = eout + ((size_t)((b*512 + l0 + T)*512) + m0 + frow)*64 + rbase;
        #pragma unroll
        for (int nb=0;nb<4;nb++){
          float4 o;
          o.x = a2[nb][0]; o.y = a2[nb][1]; o.z = a2[nb][2]; o.w = a2[nb][3];
          *reinterpret_cast<float4*>(eob + nb*16) = o;
        }
      }
    }
  }

  #pragma unroll
  for (int r=0;r<4;r++){
    float sv = Ssum[r], dv = Dsum[r];
    #pragma unroll
    for (int msk=1; msk<16; msk<<=1){ sv += __shfl_xor(sv, msk); dv += __shfl_xor(dv, msk); }
    int lrow = rbase + r;
    if (frow == 0){
      size_t idx = ((size_t)(b*512 + l0 + lrow)*8 + wv)*4 + chunk;
      Sp[idx] = sv; Dp[idx] = dv;
    }
  }
  __syncthreads();
  float* Vo = reinterpret_cast<float*>(&Eln[0][0]);   // [16][512] f32
  #pragma unroll
  for (int db=0; db<4; db++){
    #pragma unroll
    for (int r=0;r<4;r++)
      Vo[(size_t)(rbase+r)*512 + wv*64 + db*16 + frow] = accV[db][r];
  }
  __syncthreads();
  {
    int row = t>>5, i = t&31;
    u16t* vpb = Vp + ((size_t)(chunk*2048 + b*512 + l0 + row))*512 + i*16;
    const float* vsrc = &Vo[(size_t)row*512 + i*16];
    uint4 o0, o1;
    o0.x = pkbf(vsrc[0],  vsrc[1]);  o0.y = pkbf(vsrc[2],  vsrc[3]);
    o0.z = pkbf(vsrc[4],  vsrc[5]);  o0.w = pkbf(vsrc[6],  vsrc[7]);
    o1.x = pkbf(vsrc[8],  vsrc[9]);  o1.y = pkbf(vsrc[10], vsrc[11]);
    o1.z = pkbf(vsrc[12], vsrc[13]); o1.w = pkbf(vsrc[14], vsrc[15]);
    reinterpret_cast<uint4*>(vpb)[0] = o0;
    reinterpret_cast<uint4*>(vpb)[1] = o1;
  }
}

// ---------------- finalize: Va = (sum_chunks Vp) * log1p(deg)/S ----------------
__global__ __launch_bounds__(256) void kvfin(const u16t* __restrict__ Vp,
    const float* __restrict__ Sp, const float* __restrict__ Dp, u16t* __restrict__ Va)
{
  const int row = blockIdx.x;
  const int t = threadIdx.x;
  __shared__ float scl[8];
  if (t < 8){
    const float* sp = Sp + ((size_t)row*8 + t)*4;
    const float* dp = Dp + ((size_t)row*8 + t)*4;
    float S = sp[0]+sp[1]+sp[2]+sp[3];
    float D = dp[0]+dp[1]+dp[2]+dp[3];
    scl[t] = log1pf(D)/S;
  }
  __syncthreads();
  int c = t*2;
  float v0=0.f, v1=0.f;
  #pragma unroll
  for (int ch=0; ch<4; ch++){
    u32t u = *reinterpret_cast<const u32t*>(Vp + ((size_t)(ch*2048 + row))*512 + c);
    v0 += flc((u16t)(u & 0xffffu));
    v1 += flc((u16t)(u >> 16));
  }
  float s = scl[c>>6];
  *reinterpret_cast<u32t*>(Va + (size_t)row*512 + c) = pkbf(v0*s, v1*s);
}

// ---------------- LayerNorm over 512-wide rows -> bf16 ----------------
__global__ __launch_bounds__(256) void kln(const float* __restrict__ in, const float* __restrict__ g,
                                           const float* __restrict__ b, u16t* __restrict__ out){
  int wv = threadIdx.x >> 6, lane = threadIdx.x & 63;
  int row = blockIdx.x*4 + wv;
  const float4* rp = reinterpret_cast<const float4*>(in + (size_t)row*512);
  float4 v0 = rp[lane], v1 = rp[lane+64];
  float s = v0.x+v0.y+v0.z+v0.w + v1.x+v1.y+v1.z+v1.w;
  float q = v0.x*v0.x+v0.y*v0.y+v0.z*v0.z+v0.w*v0.w + v1.x*v1.x+v1.y*v1.y+v1.z*v1.z+v1.w*v1.w;
  #pragma unroll
  for (int m=1;m<64;m<<=1){ s += __shfl_xor(s,m); q += __shfl_xor(q,m); }
  float mean = s*(1.f/512.f), var = q*(1.f/512.f)-mean*mean, rs = rsqrtf(var+1e-5f);
  const float4* gp = reinterpret_cast<const float4*>(g);
  const float4* bp = reinterpret_cast<const float4*>(b);
  float4 g0=gp[lane], g1=gp[lane+64], b0=bp[lane], b1=bp[lane+64];
  u16t* op = out + (size_t)row*512;
  uint2 o0, o1;
  o0.x = pkbf((v0.x-mean)*rs*g0.x+b0.x, (v0.y-mean)*rs*g0.y+b0.y);
  o0.y = pkbf((v0.z-mean)*rs*g0.z+b0.z, (v0.w-mean)*rs*g0.w+b0.w);
  o1.x = pkbf((v1.x-mean)*rs*g1.x+b1.x, (v1.y-mean)*rs*g1.y+b1.y);
  o1.y = pkbf((v1.z-mean)*rs*g1.z+b1.z, (v1.w-mean)*rs*g1.w+b1.w);
  reinterpret_cast<uint2*>(op)[lane]    = o0;
  reinterpret_cast<uint2*>(op)[lane+64] = o1;
}

// ---------------- N-split GEMM ----------------
__global__ __launch_bounds__(256) void kgemmNS(const u16t* __restrict__ A, const u16t* __restrict__ Bt,
    const float* __restrict__ bias, const float* __restrict__ res,
    float* __restrict__ outf, u16t* __restrict__ outb, int N, int K, int do_elu)
{
  __shared__ __align__(16) u16t As[16][1032];
  const int r0 = blockIdx.x*16, t = threadIdx.x;
  {
    int row = t>>4, seg = t&15, cnt = K>>4;
    const uint4* src = reinterpret_cast<const uint4*>(A + (size_t)(r0+row)*K + seg*cnt);
    uint4* dst = reinterpret_cast<uint4*>(&As[row][seg*cnt]);
    for (int i=0;i<(cnt>>3);i++) dst[i] = src[i];
  }
  __syncthreads();
  const int wv = t>>6, lane = t&63;
  const int frow = lane&15, kgrp = (lane>>4)*8, rbase = (lane>>4)*4;
  int n0 = (blockIdx.y*4 + wv)*16;
  f32x4 acc = fz4();
  for (int k0=0;k0<K;k0+=32){
    bf16x8 af = *reinterpret_cast<const bf16x8*>(&As[frow][k0+kgrp]);
    bf16x8 bf_ = *reinterpret_cast<const bf16x8*>(Bt + (size_t)(n0+frow)*K + k0+kgrp);
    acc = MFMA(af,bf_,acc);
  }
  int col = n0 + frow;
  float bs = bias[col];
  #pragma unroll
  for (int r=0;r<4;r++){
    size_t row = (size_t)(r0 + rbase + r);
    float v = acc[r] + bs;
    if (do_elu) v = v>0.f ? v : (__expf(v)-1.f);
    if (res)  v += res[row*N + col];
    if (outf) outf[row*N + col] = v;
    if (outb) outb[row*N + col] = bfc(v);
  }
}

extern "C" void kernel_launch(void* const* d_in, const int* in_sizes, int n_in,
                              void* d_out, int out_size, void* d_ws, size_t ws_size,
                              hipStream_t stream)
{
  (void)in_sizes; (void)n_in; (void)out_size; (void)ws_size;
  const float* h      = (const float*)d_in[0];
  const float* e      = (const float*)d_in[1];
  const float* ln_h_g = (const float*)d_in[2];
  const float* ln_h_b = (const float*)d_in[3];
  const float* ln_e_g = (const float*)d_in[4];
  const float* ln_e_b = (const float*)d_in[5];
  const float* W_QKV  = (const float*)d_in[6];
  const float* b_QKV  = (const float*)d_in[7];
  const float* W_E    = (const float*)d_in[8];
  const float* b_E    = (const float*)d_in[9];
  const float* W_G    = (const float*)d_in[10];
  const float* b_G    = (const float*)d_in[11];
  const float* W_Oh   = (const float*)d_in[12];
  const float* b_Oh   = (const float*)d_in[13];
  const float* f_ln_h_g = (const float*)d_in[14];
  const float* f_ln_h_b = (const float*)d_in[15];
  const float* W_h1   = (const float*)d_in[16];
  const float* b_h1   = (const float*)d_in[17];
  const float* W_h2   = (const float*)d_in[18];
  const float* b_h2   = (const float*)d_in[19];
  const float* W_Oe   = (const float*)d_in[20];
  const float* b_Oe   = (const float*)d_in[21];
  const float* f_ln_e_g = (const float*)d_in[22];
  const float* f_ln_e_b = (const float*)d_in[23];
  const float* W_e1   = (const float*)d_in[24];
  const float* b_e1   = (const float*)d_in[25];
  const float* W_e2   = (const float*)d_in[26];
  const float* b_e2   = (const float*)d_in[27];

  float* out   = (float*)d_out;
  float* h_out = out;
  float* e_out = out + (size_t)4*512*512;

  char* w = (char*)d_ws;
  size_t off = 0;
  auto alloc = [&](size_t bytes)->char*{ char* p = w + off; off += (bytes + 255) & ~(size_t)255; return p; };
  u16t* hln   = (u16t*)alloc(2048ull*512*2);
  u16t* WtQKV = (u16t*)alloc(1536ull*512*2);
  u16t* WtOh  = (u16t*)alloc(512ull*512*2);
  u16t* WtH1  = (u16t*)alloc(1024ull*512*2);
  u16t* WtH2  = (u16t*)alloc(512ull*1024*2);
  u16t* Qb    = (u16t*)alloc(4ull*8*512*64*2);
  u16t* Kb    = (u16t*)alloc(4ull*8*512*64*2);
  u16t* Vt    = (u16t*)alloc(4ull*8*64*512*2);
  u16t* Vp    = (u16t*)alloc(4ull*2048*512*2);
  float* Sp   = (float*)alloc(4ull*512*8*4*4);
  float* Dp   = (float*)alloc(4ull*512*8*4*4);
  u16t* Va    = (u16t*)alloc(2048ull*512*2);
  float* h1   = (float*)alloc(2048ull*512*4);
  u16t* hfb   = (u16t*)alloc(2048ull*512*2);
  u16t* U     = (u16t*)alloc(2048ull*1024*2);

  kprep<<<1024, 256, 0, stream>>>(h, ln_h_g, ln_h_b, hln,
      W_QKV, WtQKV, W_Oh, WtOh, W_h1, WtH1, W_h2, WtH2);
  kqkv<<<dim3(128,6), 256, 0, stream>>>(hln, WtQKV, b_QKV, Qb, Kb, Vt);
  kattnF<<<dim3(32,4,4), 512, 0, stream>>>(e, ln_e_g, ln_e_b, W_E, b_E, W_G, b_G,
      Qb, Kb, Vt, W_Oe, b_Oe, f_ln_e_g, f_ln_e_b, W_e1, b_e1, W_e2, b_e2,
      Vp, Sp, Dp, e_out);
  kvfin<<<2048, 256, 0, stream>>>(Vp, Sp, Dp, Va);
  kgemmNS<<<dim3(128,8), 256, 0, stream>>>(Va, WtOh, b_Oh, h, h1, nullptr, 512, 512, 0);
  kln<<<512, 256, 0, stream>>>(h1, f_ln_h_g, f_ln_h_b, hfb);
  kgemmNS<<<dim3(128,16), 256, 0, stream>>>(hfb, WtH1, b_h1, nullptr, nullptr, U, 1024, 512, 1);
  kgemmNS<<<dim3(128,8), 256, 0, stream>>>(U, WtH2, b_h2, h1, h_out, nullptr, 512, 1024, 0);
}